// Round 11
// baseline (193.224 us; speedup 1.0000x reference)
//
#include <hip/hip_runtime.h>
#include <hip/hip_bf16.h>

// Problem constants
#define T_  4096
#define Bb  2
#define Nn  2048
#define Cc  768
#define Ee  24
#define Dd  64
#define Hh  12
#define KR  1600   // reduce GEMM K: 1536 (W_out) + 24 (b_out) + 40 pad (mult of 64)
#define KS  16     // gate k-split
#define KC  48     // 768 / KS
#define NB2 1024   // gate2 block count (T_/4)
#define SCL 0.18033688f   // 0.125 * log2(e) — folded into q at GEMM epilogue

typedef __attribute__((ext_vector_type(8))) short bf16x8;
typedef __attribute__((ext_vector_type(4))) short bf16x4;
typedef __attribute__((ext_vector_type(4))) float f32x4;
typedef __attribute__((ext_vector_type(8))) unsigned short u16x8;

__device__ __forceinline__ unsigned short f2bf(float f) {
  union { float f; unsigned int i; } u; u.f = f;
  unsigned int r = u.i + 0x7FFFu + ((u.i >> 16) & 1u);
  return (unsigned short)(r >> 16);
}

__device__ __forceinline__ void gload16(const void* g, void* l) {
  __builtin_amdgcn_global_load_lds(
      (const __attribute__((address_space(1))) void*)g,
      (__attribute__((address_space(3))) void*)l, 16, 0, 0);
}

// ---------------------------------------------------------------------------
// MERGED prep kernel: weight conversion + gate1 in ONE dispatch.
// The two are fully independent (convert reads W_*, gate1 reads x/wg) but
// each alone under-fills the GPU (gate1: 256 blocks = 1 block/CU!); merged
// they overlap: blocks [0,900) convert, [900,1156) gate1.
//   convert: [0,288) W_in->BqT; [288,888) [W_out;b_out;pad]->BrT;
//            [888,900) W_kv->BkvT
//   gate1:   partial logits (k-split) + fused x->bf16
// ---------------------------------------------------------------------------
#define XPAD 52
__global__ __launch_bounds__(256) void prep_kernel(
    const float* __restrict__ W_in, const float* __restrict__ W_out,
    const float* __restrict__ b_out, const float* __restrict__ W_kv,
    unsigned short* __restrict__ BqT, unsigned short* __restrict__ BrT,
    unsigned short* __restrict__ BkvT,
    const float* __restrict__ x, const float* __restrict__ wg,
    float* __restrict__ partial, unsigned short* __restrict__ xb)
{
  __shared__ __align__(16) float smem[256 * XPAD + Ee * KC];  // gate1's need (max)
  const int bid = blockIdx.x, tid = threadIdx.x;

  if (bid < 900) {
    float* ls = smem;   // convert scratch (needs <= 64*129 floats)
    if (bid < 288) {
      const int e = bid / 12, c0 = (bid % 12) * 64;
      #pragma unroll
      for (int i = 0; i < 16; ++i) {
        int L = tid + i * 256, c = L >> 6, d = L & 63;
        ls[c * 65 + d] = W_in[(size_t)e * Cc * Dd + (size_t)(c0 + c) * Dd + d];
      }
      __syncthreads();
      #pragma unroll
      for (int i = 0; i < 16; ++i) {
        int L = tid + i * 256, d = L >> 6, c = L & 63;
        BqT[(size_t)(e * Dd + d) * Cc + c0 + c] = f2bf(ls[c * 65 + d]);
      }
    } else if (bid < 888) {
      const int i2 = bid - 288;
      const int k0 = (i2 / 12) * 32, n0 = (i2 % 12) * 64;
      #pragma unroll
      for (int i = 0; i < 8; ++i) {
        int L = tid + i * 256, k = L >> 6, n = L & 63;
        int kk = k0 + k;
        float v = (kk < 1536) ? W_out[(size_t)kk * Cc + n0 + n]
                : (kk < 1560) ? b_out[(size_t)(kk - 1536) * Cc + n0 + n] : 0.f;
        ls[k * 65 + n] = v;
      }
      __syncthreads();
      #pragma unroll
      for (int i = 0; i < 8; ++i) {
        int L = tid + i * 256, n = L >> 5, k = L & 31;
        BrT[(size_t)(n0 + n) * KR + k0 + k] = f2bf(ls[k * 65 + n]);
      }
    } else {
      const int c0 = (bid - 888) * 64;
      #pragma unroll
      for (int i = 0; i < 32; ++i) {
        int L = tid + i * 256, c = L >> 7, j = L & 127;
        ls[c * 129 + j] = W_kv[(size_t)(c0 + c) * 128 + j];
      }
      __syncthreads();
      #pragma unroll
      for (int i = 0; i < 32; ++i) {
        int L = tid + i * 256, j = L >> 6, c = L & 63;
        BkvT[(size_t)j * Cc + c0 + c] = f2bf(ls[c * 129 + j]);
      }
    }
  } else {
    // ---- gate1 ----
    float* xs  = smem;
    float* wsT = smem + 256 * XPAD;
    const int g = bid - 900;
    const int t0 = (g & 15) * 256;
    const int s = g >> 4, k0 = s * KC;

    #pragma unroll
    for (int i = 0; i < 12; ++i) {
      int f = tid + i * 256;
      int token = f / 12, j = f % 12;
      size_t gofs = (size_t)(t0 + token) * Cc + k0 + j * 4;
      float4 v = *(const float4*)&x[gofs];
      *(float4*)&xs[token * XPAD + j * 4] = v;
      ushort4 o;
      o.x = f2bf(v.x); o.y = f2bf(v.y); o.z = f2bf(v.z); o.w = f2bf(v.w);
      *(ushort4*)&xb[gofs] = o;
    }
    for (int i = tid; i < Ee * KC; i += 256)
      wsT[(i % Ee) * KC + i / Ee] = wg[k0 * Ee + i];
    __syncthreads();

    float xr[KC];
    #pragma unroll
    for (int kg = 0; kg < KC / 4; ++kg)
      *(float4*)&xr[kg * 4] = *(const float4*)&xs[tid * XPAD + kg * 4];

    float acc[Ee];
    #pragma unroll
    for (int e = 0; e < Ee; ++e) acc[e] = 0.f;
    #pragma unroll
    for (int e = 0; e < Ee; ++e) {
      #pragma unroll
      for (int kg = 0; kg < KC / 4; ++kg) {
        float4 wv = *(const float4*)&wsT[e * KC + kg * 4];
        acc[e] += xr[kg * 4 + 0] * wv.x + xr[kg * 4 + 1] * wv.y
                + xr[kg * 4 + 2] * wv.z + xr[kg * 4 + 3] * wv.w;
      }
    }

    float* dst = partial + ((size_t)(t0 + tid) * KS + s) * Ee;
    #pragma unroll
    for (int eg = 0; eg < Ee / 4; ++eg)
      *(float4*)&dst[eg * 4] = *(float4*)&acc[eg * 4];
  }
}

// ---------------------------------------------------------------------------
// bf16 MFMA GEMM: C = A[M][K] @ BT[N][K]^T (+bias).  Tile BM x BN, BK=64.
// R9 structure (validated win): 2-phase double-buffer, halved barrier count,
// attn-style XOR-swizzled LDS staging/reads (zero bank conflicts).
// NEW: BM/BN templated.  qkv uses 128x64 (16 MFMA : 12 ds_read per K-step,
// 25% less staged bytes/FLOP, grid 832 = 3.25/CU — above the 1.5/CU
// starvation regime that killed R3's 128-tile).  reduce stays 64x64.
// MODE 0: f32 out (reduce GEMM).  MODE 1: fused qall+kv epilogue.
// ---------------------------------------------------------------------------
template<int MODE, int BM, int BN>
__global__ __launch_bounds__(256) void gemm_bt_kernel(
    const unsigned short* __restrict__ A, const unsigned short* __restrict__ BT,
    const float* __restrict__ bias, const float* __restrict__ bias2,
    void* __restrict__ Cout, void* __restrict__ Cout2, void* __restrict__ Cout3,
    int K, int ldc)
{
  constexpr int MI = BM / 32, NI = BN / 32;
  __shared__ __align__(16) unsigned short As[2][BM * 64];
  __shared__ __align__(16) unsigned short Bs[2][BN * 64];
  const int tid = threadIdx.x, w = tid >> 6, lane = tid & 63;
  const int quad = lane >> 4, nl = lane & 15;
  const int m0 = blockIdx.x * BM, n0 = blockIdx.y * BN;
  const int mw = (w & 1) * (BM / 2), nw = (w >> 1) * (BN / 2);

  f32x4 acc[MI][NI];
  #pragma unroll
  for (int i = 0; i < MI; ++i)
    #pragma unroll
    for (int j = 0; j < NI; ++j) acc[i][j] = (f32x4){0.f, 0.f, 0.f, 0.f};

  // attn-style swizzled staging/read offsets (verified 0 bank conflicts)
  const int sr  = lane >> 3;                 // row within 8-row stage chunk
  const int cbd = (lane & 7) ^ sr;           // pre-swizzled source chunk
  const int xl  = nl & 7;
  const int ca0 = (quad ^ xl) * 8;           // K-half 0 chunk offset (shorts)
  const int ca1 = ((quad + 4) ^ xl) * 8;     // K-half 1

  const unsigned short* abase = A + (size_t)(m0 + w * (BM / 4) + sr) * K + cbd * 8;
  const unsigned short* bbase = BT + (size_t)(n0 + w * (BN / 4) + sr) * K + cbd * 8;

  auto STAGE = [&](int bi, int k0) {
    #pragma unroll
    for (int i = 0; i < BM / 32; ++i)
      gload16(abase + (size_t)(i * 8) * K + k0,
              &As[bi][(w * (BM / 4) + i * 8) * 64]);
    #pragma unroll
    for (int i = 0; i < BN / 32; ++i)
      gload16(bbase + (size_t)(i * 8) * K + k0,
              &Bs[bi][(w * (BN / 4) + i * 8) * 64]);
  };

  const int nt = K / 64;
  STAGE(0, 0);
  __syncthreads();
  for (int t = 0; t < nt; ++t) {
    const int cur = t & 1;
    if (t + 1 < nt) STAGE(cur ^ 1, (t + 1) * 64);   // issue next BEFORE compute

    bf16x8 af0[MI], af1[MI], bf0[NI], bf1[NI];
    #pragma unroll
    for (int mi = 0; mi < MI; ++mi) {
      const unsigned short* ar = &As[cur][(mw + mi * 16 + nl) * 64];
      af0[mi] = *(const bf16x8*)(ar + ca0);
      af1[mi] = *(const bf16x8*)(ar + ca1);
    }
    #pragma unroll
    for (int ni = 0; ni < NI; ++ni) {
      const unsigned short* br = &Bs[cur][(nw + ni * 16 + nl) * 64];
      bf0[ni] = *(const bf16x8*)(br + ca0);
      bf1[ni] = *(const bf16x8*)(br + ca1);
    }
    #pragma unroll
    for (int mi = 0; mi < MI; ++mi)
      #pragma unroll
      for (int ni = 0; ni < NI; ++ni) {
        acc[mi][ni] = __builtin_amdgcn_mfma_f32_16x16x32_bf16(
            af0[mi], bf0[ni], acc[mi][ni], 0, 0, 0);
        acc[mi][ni] = __builtin_amdgcn_mfma_f32_16x16x32_bf16(
            af1[mi], bf1[ni], acc[mi][ni], 0, 0, 0);
      }

    __syncthreads();   // drain overlaps: loads had the compute phase to land
  }

  #pragma unroll
  for (int mi = 0; mi < MI; ++mi) {
    int rowb = m0 + mw + mi * 16 + quad * 4;
    int bb = rowb >> 11, nn = rowb & (Nn - 1);
    #pragma unroll
    for (int ni = 0; ni < NI; ++ni) {
      int col = n0 + nw + ni * 16 + nl;
      if (MODE == 0) {
        #pragma unroll
        for (int reg = 0; reg < 4; ++reg)
          ((float*)Cout)[(size_t)(rowb + reg) * ldc + col] = acc[mi][ni][reg];
      } else {
        if (col < 1536) {
          float bv = bias[col];
          #pragma unroll
          for (int reg = 0; reg < 4; ++reg)
            ((unsigned short*)Cout)[(size_t)(rowb + reg) * 1536 + col] =
                f2bf((acc[mi][ni][reg] + bv) * SCL);
        } else {
          int c2 = col - 1536;
          float bv = bias2[c2];
          if (c2 < Dd) {
            #pragma unroll
            for (int reg = 0; reg < 4; ++reg)
              ((unsigned short*)Cout2)[((size_t)bb * Nn + nn + reg) * Dd + c2] =
                  f2bf(acc[mi][ni][reg] + bv);
          } else {
            int p6 = nn & 63;
            int np = (nn & ~63) | (p6 & 0x23)
                   | (((p6 >> 4) & 1) << 2) | (((p6 >> 2) & 3) << 3);
            ushort4 v;
            v.x = f2bf(acc[mi][ni][0] + bv);
            v.y = f2bf(acc[mi][ni][1] + bv);
            v.z = f2bf(acc[mi][ni][2] + bv);
            v.w = f2bf(acc[mi][ni][3] + bv);
            *(ushort4*)((unsigned short*)Cout3 +
                        ((size_t)bb * Dd + (c2 - Dd)) * Nn + np) = v;
          }
        }
      }
    }
  }
}

// ---------------------------------------------------------------------------
// gate2: logits -> softmax -> top-12 -> gates; block stats -> bstats.
// Also preps each token's xeg row (zero-fill + dense-gate cols) for the
// scatter-free pipeline.
// ---------------------------------------------------------------------------
__global__ __launch_bounds__(256) void gate2_kernel(
    const float* __restrict__ partial,
    int* __restrict__ idx, float* __restrict__ gate, float* __restrict__ bstats,
    unsigned short* __restrict__ xeg)
{
  __shared__ float xls[4][KS * Ee];
  __shared__ float sacc[49];
  __shared__ unsigned short dens[4][64];
  const int tid = threadIdx.x;
  const int w = tid >> 6, lane = tid & 63;
  const int t = blockIdx.x * 4 + w;

  if (tid < 49) sacc[tid] = 0.f;
  dens[w][lane] = 0;

  const float* p = partial + (size_t)t * (KS * Ee);
  #pragma unroll
  for (int i = 0; i < 6; ++i) xls[w][lane + i * 64] = p[lane + i * 64];

  // zero-fill xeg cols [0,1536) for this token (3 x ushort8 per lane)
  {
    u16x8 z = (u16x8){0, 0, 0, 0, 0, 0, 0, 0};
    unsigned short* xrow = xeg + (size_t)t * KR;
    #pragma unroll
    for (int i = 0; i < 3; ++i)
      *(u16x8*)&xrow[(lane + i * 64) * 8] = z;
  }

  float logit = -1e30f;
  if (lane < Ee) {
    float acc = 0.f;
    #pragma unroll
    for (int s = 0; s < KS; ++s) acc += xls[w][s * Ee + lane];
    logit = acc;
  }
  float m = logit;
  for (int o = 32; o; o >>= 1) m = fmaxf(m, __shfl_xor(m, o));
  float pr = (lane < Ee) ? expf(logit - m) : 0.f;
  float s = pr;
  for (int o = 32; o; o >>= 1) s += __shfl_xor(s, o);
  float prob = pr / s;
  float lse = m + logf(s);

  bool sel = false;
  float my_p = 0.f; int my_e = -1;
  for (int h = 0; h < Hh; ++h) {
    float v = (lane < Ee && !sel) ? prob : -1.f;
    int ix = lane;
    for (int o = 32; o; o >>= 1) {
      float ov = __shfl_xor(v, o); int oi = __shfl_xor(ix, o);
      if (ov > v || (ov == v && oi < ix)) { v = ov; ix = oi; }
    }
    if (lane == ix) sel = true;
    if (lane == h) { my_p = v; my_e = ix; }
  }
  float gsum = (lane < Hh) ? my_p : 0.f;
  for (int o = 32; o; o >>= 1) gsum += __shfl_xor(gsum, o);
  float gval = my_p / (gsum + 1e-6f);
  if (lane < Hh) {
    idx[t * Hh + lane] = my_e;
    gate[t * Hh + lane] = gval;
  }

  __syncthreads();
  if (lane < Ee) atomicAdd(&sacc[lane], prob);
  if (lane < Hh) {
    atomicAdd(&sacc[24 + my_e], 1.0f);
    dens[w][my_e] = f2bf(gval);
  }
  if (lane == 0) atomicAdd(&sacc[48], lse * lse);
  __syncthreads();
  if (tid < 49) bstats[(size_t)tid * NB2 + blockIdx.x] = sacc[tid];

  // dense-gate + pad cols [1536,1600): one short per lane
  xeg[(size_t)t * KR + 1536 + lane] = dens[w][lane];
}

// ---------------------------------------------------------------------------
// Flash attention with FUSED combine epilogue (R10 win config — unchanged).
// Core loop: transposed, 16 q/wave, in-register P, PV at K=32, 3-deep
// rotating LDS buffers (48 KB), 2-tile prefetch, counted vmcnt(8).
// Epilogue writes f2bf(gate * o / l) straight into xeg.
// ---------------------------------------------------------------------------
__global__ __launch_bounds__(256, 3) void attn_kernel(
    const unsigned short* __restrict__ qallb, const int* __restrict__ idx,
    const float* __restrict__ gate,
    const unsigned short* __restrict__ kbuf, const unsigned short* __restrict__ vtbuf,
    unsigned short* __restrict__ xeg)
{
  __shared__ __align__(16) unsigned short ksl[3][64 * 64];  // K tiles [key][d], swizzled
  __shared__ __align__(16) unsigned short vtl[3][64 * 64];  // V^T tiles [d][key-perm]

  const int tid = threadIdx.x;
  const int w = tid >> 6, lane = tid & 63;
  const int quad = lane >> 4, nl = lane & 15;
  const int bh = blockIdx.y;
  const int b = bh / Hh, h = bh - b * Hh;
  const int qw = blockIdx.x * 64 + w * 16;      // wave's 16 queries

  // Q B-frags (gathered via expert idx; pre-scaled by SCL at GEMM epilogue)
  const int tq = b * Nn + qw + nl;
  const int eq = idx[tq * Hh + h];
  const unsigned short* qrow = qallb + (size_t)tq * (Ee * Dd) + eq * Dd + quad * 8;
  const bf16x8 qB0 = *(const bf16x8*)(qrow);
  const bf16x8 qB1 = *(const bf16x8*)(qrow + 32);

  f32x4 acc[4];
  #pragma unroll
  for (int dg = 0; dg < 4; ++dg) acc[dg] = (f32x4){0.f, 0.f, 0.f, 0.f};
  float l = 0.f;

  const int sr  = lane >> 3;
  const int cbd = (lane & 7) ^ sr;              // XOR-swizzled source chunk
  const int xl  = nl & 7;
  const int ca0 = (quad ^ xl) * 8;              // b128 chunk offsets (K and V)
  const int ca1 = ((quad + 4) ^ xl) * 8;

  // wave-level staging bases (each wave stages rows w*16..w*16+15 of a tile)
  const unsigned short* kgbase =
      kbuf + ((size_t)b * Nn + w * 16 + sr) * Dd + cbd * 8;
  const unsigned short* vgbase =
      vtbuf + ((size_t)b * Dd + w * 16 + sr) * Nn + cbd * 8;

  auto STAGE = [&](int bi, int t) {
    const int j0 = t * 64;
    #pragma unroll
    for (int i = 0; i < 2; ++i) {
      gload16(kgbase + (size_t)(j0 + i * 8) * Dd, &ksl[bi][(w * 16 + i * 8) * 64]);
      gload16(vgbase + (size_t)(i * 8) * Nn + j0, &vtl[bi][(w * 16 + i * 8) * 64]);
    }
  };

  auto COMPUTE = [&](const unsigned short* ks_, const unsigned short* vt_) {
    __builtin_amdgcn_s_setprio(1);
    // --- S^T = K·Q^T ---
    bf16x4 pf[4];
    #pragma unroll
    for (int kg = 0; kg < 4; ++kg) {
      const unsigned short* kr = ks_ + (kg * 16 + nl) * 64;
      bf16x8 a0 = *(const bf16x8*)(kr + ca0);
      bf16x8 a1 = *(const bf16x8*)(kr + ca1);
      f32x4 c = {0.f, 0.f, 0.f, 0.f};
      c = __builtin_amdgcn_mfma_f32_16x16x32_bf16(a0, qB0, c, 0, 0, 0);
      c = __builtin_amdgcn_mfma_f32_16x16x32_bf16(a1, qB1, c, 0, 0, 0);
      float p0 = __builtin_amdgcn_exp2f(c[0]);
      float p1 = __builtin_amdgcn_exp2f(c[1]);
      float p2 = __builtin_amdgcn_exp2f(c[2]);
      float p3 = __builtin_amdgcn_exp2f(c[3]);
      l += (p0 + p1) + (p2 + p3);
      union { __hip_bfloat162 h2[2]; bf16x4 v; } pk;
      pk.h2[0] = __float22bfloat162_rn(float2{p0, p1});
      pk.h2[1] = __float22bfloat162_rn(float2{p2, p3});
      pf[kg] = pk.v;
    }
    bf16x8 pb0 = __builtin_shufflevector(pf[0], pf[1], 0, 1, 2, 3, 4, 5, 6, 7);
    bf16x8 pb1 = __builtin_shufflevector(pf[2], pf[3], 0, 1, 2, 3, 4, 5, 6, 7);
    // --- O^T += V^T·P^T at K=32 ---
    #pragma unroll
    for (int dg = 0; dg < 4; ++dg) {
      const unsigned short* vrow = vt_ + (dg * 16 + nl) * 64;
      bf16x8 v0 = *(const bf16x8*)(vrow + ca0);
      bf16x8 v1 = *(const bf16x8*)(vrow + ca1);
      acc[dg] = __builtin_amdgcn_mfma_f32_16x16x32_bf16(v0, pb0, acc[dg], 0, 0, 0);
      acc[dg] = __builtin_amdgcn_mfma_f32_16x16x32_bf16(v1, pb1, acc[dg], 0, 0, 0);
    }
    __builtin_amdgcn_s_setprio(0);
  };

  // ---- software pipeline: 32 tiles, 2-deep prefetch, 3 rotating buffers ----
  STAGE(0, 0);
  STAGE(1, 1);
  #pragma unroll 1
  for (int t = 0; t < 30; t += 3) {
    STAGE(2, t + 2);
    asm volatile("s_waitcnt vmcnt(8)" ::: "memory");
    __builtin_amdgcn_s_barrier();
    __builtin_amdgcn_sched_barrier(0);
    COMPUTE(ksl[0], vtl[0]);
    __builtin_amdgcn_sched_barrier(0);
    asm volatile("" ::: "memory");
    __builtin_amdgcn_s_barrier();

    STAGE(0, t + 3);
    asm volatile("s_waitcnt vmcnt(8)" ::: "memory");
    __builtin_amdgcn_s_barrier();
    __builtin_amdgcn_sched_barrier(0);
    COMPUTE(ksl[1], vtl[1]);
    __builtin_amdgcn_sched_barrier(0);
    asm volatile("" ::: "memory");
    __builtin_amdgcn_s_barrier();

    STAGE(1, t + 4);
    asm volatile("s_waitcnt vmcnt(8)" ::: "memory");
    __builtin_amdgcn_s_barrier();
    __builtin_amdgcn_sched_barrier(0);
    COMPUTE(ksl[2], vtl[2]);
    __builtin_amdgcn_sched_barrier(0);
    asm volatile("" ::: "memory");
    __builtin_amdgcn_s_barrier();
  }
  asm volatile("s_waitcnt vmcnt(4)" ::: "memory");
  __builtin_amdgcn_s_barrier();
  __builtin_amdgcn_sched_barrier(0);
  COMPUTE(ksl[0], vtl[0]);
  __builtin_amdgcn_sched_barrier(0);
  asm volatile("s_waitcnt vmcnt(0)" ::: "memory");
  __builtin_amdgcn_s_barrier();
  __builtin_amdgcn_sched_barrier(0);
  COMPUTE(ksl[1], vtl[1]);

  // ---- fused combine epilogue: xeg[tq][eq*64 + d] = f2bf(gate * o / l) ----
  float lg = l;
  lg += __shfl_xor(lg, 16);
  lg += __shfl_xor(lg, 32);                      // full softmax sum for query nl
  const float scale = gate[tq * Hh + h] / lg;
  unsigned short* xrow = xeg + (size_t)tq * KR + eq * Dd + quad * 4;
  #pragma unroll
  for (int dg = 0; dg < 4; ++dg) {
    ushort4 v;
    v.x = f2bf(acc[dg][0] * scale);
    v.y = f2bf(acc[dg][1] * scale);
    v.z = f2bf(acc[dg][2] * scale);
    v.w = f2bf(acc[dg][3] * scale);
    *(ushort4*)(xrow + dg * 16) = v;
  }
}

// ---------------------------------------------------------------------------
// aux1: parallel bstats row-sum -> stats2[49];  aux2: finalize
// ---------------------------------------------------------------------------
__global__ __launch_bounds__(256) void aux1_kernel(
    const float* __restrict__ bstats, float* __restrict__ stats2)
{
  __shared__ float r[4];
  const int j = blockIdx.x, tid = threadIdx.x;
  float4 v = *(const float4*)&bstats[(size_t)j * NB2 + tid * 4];
  float s = (v.x + v.y) + (v.z + v.w);
  for (int o = 32; o; o >>= 1) s += __shfl_xor(s, o);
  if ((tid & 63) == 0) r[tid >> 6] = s;
  __syncthreads();
  if (tid == 0) stats2[j] = (r[0] + r[1]) + (r[2] + r[3]);
}

__global__ void aux2_kernel(const float* __restrict__ stats2,
                            float* __restrict__ out, int out_size)
{
  const int lane = threadIdx.x;
  float a = (lane < Ee) ? stats2[lane] : 0.f;
  float b = (lane < Ee) ? stats2[24 + lane] : 0.f;
  float pt = a, ft = b, sw = a * b;
  for (int o = 32; o; o >>= 1) {
    pt += __shfl_xor(pt, o); ft += __shfl_xor(ft, o); sw += __shfl_xor(sw, o);
  }
  if (lane == 0) {
    float sswitch = (float)Ee * sw / (pt * ft);
    float z = stats2[48] * (1.0f / (float)T_);
    out[out_size - 1] = 0.1f * sswitch + 0.001f * z;
  }
}

// ---------------------------------------------------------------------------
extern "C" void kernel_launch(void* const* d_in, const int* in_sizes, int n_in,
                              void* d_out, int out_size, void* d_ws, size_t ws_size,
                              hipStream_t stream)
{
  const float* x     = (const float*)d_in[0];
  const float* wg    = (const float*)d_in[1];
  const float* W_in  = (const float*)d_in[2];
  const float* b_in  = (const float*)d_in[3];
  const float* W_out = (const float*)d_in[4];
  const float* b_out = (const float*)d_in[5];
  const float* W_kv  = (const float*)d_in[6];
  const float* b_kv  = (const float*)d_in[7];
  float* out = (float*)d_out;

  char* ws = (char*)d_ws;
  size_t off = 0;
  auto carve = [&](size_t bytes) -> void* {
    void* p = ws + off;
    off = (off + bytes + 255) & ~(size_t)255;
    return p;
  };
  int*            idx    = (int*)           carve((size_t)T_ * Hh * 4);
  float*          gate   = (float*)         carve((size_t)T_ * Hh * 4);
  float*          bstats = (float*)         carve((size_t)49 * NB2 * 4);
  float*          stats2 = (float*)         carve(256);
  float*          lgate  = (float*)         carve((size_t)T_ * KS * Ee * 4);
  unsigned short* xb     = (unsigned short*)carve((size_t)T_ * Cc * 2);
  unsigned short* BqkvT  = (unsigned short*)carve((size_t)(Ee * Dd + 128) * Cc * 2);
  unsigned short* BkvT   = BqkvT + (size_t)Ee * Dd * Cc;
  unsigned short* BrT    = (unsigned short*)carve((size_t)Cc * KR * 2);
  unsigned short* kbuf   = (unsigned short*)carve((size_t)T_ * Dd * 2);
  unsigned short* vtbuf  = (unsigned short*)carve((size_t)T_ * Dd * 2);
  unsigned short* qallb  = (unsigned short*)carve((size_t)T_ * Ee * Dd * 2);
  unsigned short* xeg    = (unsigned short*)carve((size_t)T_ * KR * 2);

  // merged weight conversion + gate1 (independent work, one dispatch)
  prep_kernel<<<1156, 256, 0, stream>>>(
      W_in, W_out, b_out, W_kv, BqkvT, BrT, BkvT, x, wg, lgate, xb);

  // gate2 (softmax/top-k/stats + xeg row prep)
  gate2_kernel<<<NB2, 256, 0, stream>>>(lgate, idx, gate, bstats, xeg);

  // fused qall + kv GEMM: 128x64 tiles, BK=64, grid (32, 26) = 832 blocks
  gemm_bt_kernel<1, 128, 64><<<dim3(T_ / 128, 26), 256, 0, stream>>>(
      xb, BqkvT, b_in, b_kv, qallb, kbuf, vtbuf, Cc, 1536);

  // attention with fused combine epilogue -> xeg
  attn_kernel<<<dim3(Nn / 64, Bb * Hh), 256, 0, stream>>>(
      qallb, idx, gate, kbuf, vtbuf, xeg);

  // out = xeg @ BrT^T -> f32: 64x64 tiles, BK=64, grid (64, 12)
  gemm_bt_kernel<0, 64, 64><<<dim3(T_ / 64, Cc / 64), 256, 0, stream>>>(
      xeg, BrT, nullptr, nullptr, out, nullptr, nullptr, KR, Cc);

  // aux loss
  aux1_kernel<<<49, 256, 0, stream>>>(bstats, stats2);
  aux2_kernel<<<1, 64, 0, stream>>>(stats2, out, out_size);
}

// Round 13
// 179.610 us; speedup vs baseline: 1.0758x; 1.0758x over previous
//
#include <hip/hip_runtime.h>
#include <hip/hip_bf16.h>

// Problem constants
#define T_  4096
#define Bb  2
#define Nn  2048
#define Cc  768
#define Ee  24
#define Dd  64
#define Hh  12
#define KR  1600   // reduce GEMM K: 1536 (W_out) + 24 (b_out) + 40 pad (mult of 64)
#define KS  16     // gate k-split
#define KC  48     // 768 / KS
#define NB2 1024   // gate2 block count (T_/4)
#define SCL 0.18033688f   // 0.125 * log2(e) — folded into q at GEMM epilogue

typedef __attribute__((ext_vector_type(8))) short bf16x8;
typedef __attribute__((ext_vector_type(4))) short bf16x4;
typedef __attribute__((ext_vector_type(4))) float f32x4;
typedef __attribute__((ext_vector_type(8))) unsigned short u16x8;

__device__ __forceinline__ unsigned short f2bf(float f) {
  union { float f; unsigned int i; } u; u.f = f;
  unsigned int r = u.i + 0x7FFFu + ((u.i >> 16) & 1u);
  return (unsigned short)(r >> 16);
}

__device__ __forceinline__ void gload16(const void* g, void* l) {
  __builtin_amdgcn_global_load_lds(
      (const __attribute__((address_space(1))) void*)g,
      (__attribute__((address_space(3))) void*)l, 16, 0, 0);
}

// ---------------------------------------------------------------------------
// MERGED prep kernel (occupancy-fixed vs R11): weight conversion + gate1.
// R11's version forced 56.5 KB LDS on all blocks -> 2 blocks/CU -> regression.
// Fix: gate1 sub-blocks handle 128 tokens (2 threads/token, 12 experts each),
// so gate1 needs 128*52+1152 floats = 30.5 KB < convert's 33 KB.  Merged
// smem = 64*129 floats = 33 KB -> 4 blocks/CU (same class as separate).
//   blocks [0,288)     : W_in -> BqT
//   blocks [288,888)   : [W_out;b_out;pad] -> BrT
//   blocks [888,900)   : W_kv -> BkvT
//   blocks [900,1412)  : gate1 (512 blocks: 32 t-chunks x 16 k-slices)
// ---------------------------------------------------------------------------
#define XPAD 52
__global__ __launch_bounds__(256) void prep_kernel(
    const float* __restrict__ W_in, const float* __restrict__ W_out,
    const float* __restrict__ b_out, const float* __restrict__ W_kv,
    unsigned short* __restrict__ BqT, unsigned short* __restrict__ BrT,
    unsigned short* __restrict__ BkvT,
    const float* __restrict__ x, const float* __restrict__ wg,
    float* __restrict__ partial, unsigned short* __restrict__ xb)
{
  __shared__ __align__(16) float smem[64 * 129];   // 33 KB (max of both uses)
  const int bid = blockIdx.x, tid = threadIdx.x;

  if (bid < 900) {
    float* ls = smem;
    if (bid < 288) {
      const int e = bid / 12, c0 = (bid % 12) * 64;
      #pragma unroll
      for (int i = 0; i < 16; ++i) {
        int L = tid + i * 256, c = L >> 6, d = L & 63;
        ls[c * 65 + d] = W_in[(size_t)e * Cc * Dd + (size_t)(c0 + c) * Dd + d];
      }
      __syncthreads();
      #pragma unroll
      for (int i = 0; i < 16; ++i) {
        int L = tid + i * 256, d = L >> 6, c = L & 63;
        BqT[(size_t)(e * Dd + d) * Cc + c0 + c] = f2bf(ls[c * 65 + d]);
      }
    } else if (bid < 888) {
      const int i2 = bid - 288;
      const int k0 = (i2 / 12) * 32, n0 = (i2 % 12) * 64;
      #pragma unroll
      for (int i = 0; i < 8; ++i) {
        int L = tid + i * 256, k = L >> 6, n = L & 63;
        int kk = k0 + k;
        float v = (kk < 1536) ? W_out[(size_t)kk * Cc + n0 + n]
                : (kk < 1560) ? b_out[(size_t)(kk - 1536) * Cc + n0 + n] : 0.f;
        ls[k * 65 + n] = v;
      }
      __syncthreads();
      #pragma unroll
      for (int i = 0; i < 8; ++i) {
        int L = tid + i * 256, n = L >> 5, k = L & 31;
        BrT[(size_t)(n0 + n) * KR + k0 + k] = f2bf(ls[k * 65 + n]);
      }
    } else {
      const int c0 = (bid - 888) * 64;
      #pragma unroll
      for (int i = 0; i < 32; ++i) {
        int L = tid + i * 256, c = L >> 7, j = L & 127;
        ls[c * 129 + j] = W_kv[(size_t)(c0 + c) * 128 + j];
      }
      __syncthreads();
      #pragma unroll
      for (int i = 0; i < 32; ++i) {
        int L = tid + i * 256, j = L >> 6, c = L & 63;
        BkvT[(size_t)j * Cc + c0 + c] = f2bf(ls[c * 129 + j]);
      }
    }
  } else {
    // ---- gate1: 128 tokens/block, 2 threads per token ----
    float* xs  = smem;                 // 128 * XPAD floats
    float* wsT = smem + 128 * XPAD;    // Ee * KC floats
    const int g = bid - 900;
    const int t0 = (g & 31) * 128;
    const int s = g >> 5, k0 = s * KC;

    // stage x (128 tokens x 48 floats = 1536 float4 / 256 threads = 6 each)
    #pragma unroll
    for (int i = 0; i < 6; ++i) {
      int f = tid + i * 256;
      int token = f / 12, j = f % 12;
      size_t gofs = (size_t)(t0 + token) * Cc + k0 + j * 4;
      float4 v = *(const float4*)&x[gofs];
      *(float4*)&xs[token * XPAD + j * 4] = v;
      ushort4 o;
      o.x = f2bf(v.x); o.y = f2bf(v.y); o.z = f2bf(v.z); o.w = f2bf(v.w);
      *(ushort4*)&xb[gofs] = o;
    }
    for (int i = tid; i < Ee * KC; i += 256)
      wsT[(i % Ee) * KC + i / Ee] = wg[k0 * Ee + i];
    __syncthreads();

    const int token = tid >> 1, half = tid & 1;   // 2 threads per token
    float xr[KC];
    #pragma unroll
    for (int kg = 0; kg < KC / 4; ++kg)
      *(float4*)&xr[kg * 4] = *(const float4*)&xs[token * XPAD + kg * 4];

    float acc[12];
    #pragma unroll
    for (int e = 0; e < 12; ++e) acc[e] = 0.f;
    #pragma unroll
    for (int e = 0; e < 12; ++e) {
      const int eg = half * 12 + e;
      #pragma unroll
      for (int kg = 0; kg < KC / 4; ++kg) {
        float4 wv = *(const float4*)&wsT[eg * KC + kg * 4];
        acc[e] += xr[kg * 4 + 0] * wv.x + xr[kg * 4 + 1] * wv.y
                + xr[kg * 4 + 2] * wv.z + xr[kg * 4 + 3] * wv.w;
      }
    }

    float* dst = partial + ((size_t)(t0 + token) * KS + s) * Ee + half * 12;
    #pragma unroll
    for (int eg2 = 0; eg2 < 3; ++eg2)
      *(float4*)&dst[eg2 * 4] = *(float4*)&acc[eg2 * 4];
  }
}

// ---------------------------------------------------------------------------
// bf16 MFMA GEMM: C = A[M][K] @ BT[N][K]^T (+bias).  Tile 64x64, BK=64.
// R9/R10 structure (validated): 2-phase double-buffer, halved barrier count,
// attn-style XOR-swizzled LDS staging/reads (zero bank conflicts).
// MODE 0: f32 out (reduce GEMM).  MODE 1: fused qall+kv epilogue.
// ---------------------------------------------------------------------------
template<int MODE>
__global__ __launch_bounds__(256) void gemm_bt_kernel(
    const unsigned short* __restrict__ A, const unsigned short* __restrict__ BT,
    const float* __restrict__ bias, const float* __restrict__ bias2,
    void* __restrict__ Cout, void* __restrict__ Cout2, void* __restrict__ Cout3,
    int K, int ldc)
{
  constexpr int BM = 64, BN = 64, MI = 2, NI = 2;
  __shared__ __align__(16) unsigned short As[2][BM * 64];
  __shared__ __align__(16) unsigned short Bs[2][BN * 64];
  const int tid = threadIdx.x, w = tid >> 6, lane = tid & 63;
  const int quad = lane >> 4, nl = lane & 15;
  const int m0 = blockIdx.x * BM, n0 = blockIdx.y * BN;
  const int mw = (w & 1) * 32, nw = (w >> 1) * 32;

  f32x4 acc[MI][NI];
  #pragma unroll
  for (int i = 0; i < MI; ++i)
    #pragma unroll
    for (int j = 0; j < NI; ++j) acc[i][j] = (f32x4){0.f, 0.f, 0.f, 0.f};

  // attn-style swizzled staging/read offsets (verified 0 bank conflicts)
  const int sr  = lane >> 3;                 // row within 8-row stage chunk
  const int cbd = (lane & 7) ^ sr;           // pre-swizzled source chunk
  const int xl  = nl & 7;
  const int ca0 = (quad ^ xl) * 8;           // K-half 0 chunk offset (shorts)
  const int ca1 = ((quad + 4) ^ xl) * 8;     // K-half 1

  const unsigned short* abase = A + (size_t)(m0 + w * 16 + sr) * K + cbd * 8;
  const unsigned short* bbase = BT + (size_t)(n0 + w * 16 + sr) * K + cbd * 8;

  auto STAGE = [&](int bi, int k0) {
    #pragma unroll
    for (int i = 0; i < 2; ++i) {
      gload16(abase + (size_t)(i * 8) * K + k0, &As[bi][(w * 16 + i * 8) * 64]);
      gload16(bbase + (size_t)(i * 8) * K + k0, &Bs[bi][(w * 16 + i * 8) * 64]);
    }
  };

  const int nt = K / 64;
  STAGE(0, 0);
  __syncthreads();
  for (int t = 0; t < nt; ++t) {
    const int cur = t & 1;
    if (t + 1 < nt) STAGE(cur ^ 1, (t + 1) * 64);   // issue next BEFORE compute

    bf16x8 af0[MI], af1[MI], bf0[NI], bf1[NI];
    #pragma unroll
    for (int mi = 0; mi < MI; ++mi) {
      const unsigned short* ar = &As[cur][(mw + mi * 16 + nl) * 64];
      af0[mi] = *(const bf16x8*)(ar + ca0);
      af1[mi] = *(const bf16x8*)(ar + ca1);
    }
    #pragma unroll
    for (int ni = 0; ni < NI; ++ni) {
      const unsigned short* br = &Bs[cur][(nw + ni * 16 + nl) * 64];
      bf0[ni] = *(const bf16x8*)(br + ca0);
      bf1[ni] = *(const bf16x8*)(br + ca1);
    }
    #pragma unroll
    for (int mi = 0; mi < MI; ++mi)
      #pragma unroll
      for (int ni = 0; ni < NI; ++ni) {
        acc[mi][ni] = __builtin_amdgcn_mfma_f32_16x16x32_bf16(
            af0[mi], bf0[ni], acc[mi][ni], 0, 0, 0);
        acc[mi][ni] = __builtin_amdgcn_mfma_f32_16x16x32_bf16(
            af1[mi], bf1[ni], acc[mi][ni], 0, 0, 0);
      }

    __syncthreads();   // drain overlaps: loads had the compute phase to land
  }

  #pragma unroll
  for (int mi = 0; mi < MI; ++mi) {
    int rowb = m0 + mw + mi * 16 + quad * 4;
    int bb = rowb >> 11, nn = rowb & (Nn - 1);
    #pragma unroll
    for (int ni = 0; ni < NI; ++ni) {
      int col = n0 + nw + ni * 16 + nl;
      if (MODE == 0) {
        #pragma unroll
        for (int reg = 0; reg < 4; ++reg)
          ((float*)Cout)[(size_t)(rowb + reg) * ldc + col] = acc[mi][ni][reg];
      } else {
        if (col < 1536) {
          float bv = bias[col];
          #pragma unroll
          for (int reg = 0; reg < 4; ++reg)
            ((unsigned short*)Cout)[(size_t)(rowb + reg) * 1536 + col] =
                f2bf((acc[mi][ni][reg] + bv) * SCL);
        } else {
          int c2 = col - 1536;
          float bv = bias2[c2];
          if (c2 < Dd) {
            #pragma unroll
            for (int reg = 0; reg < 4; ++reg)
              ((unsigned short*)Cout2)[((size_t)bb * Nn + nn + reg) * Dd + c2] =
                  f2bf(acc[mi][ni][reg] + bv);
          } else {
            int p6 = nn & 63;
            int np = (nn & ~63) | (p6 & 0x23)
                   | (((p6 >> 4) & 1) << 2) | (((p6 >> 2) & 3) << 3);
            ushort4 v;
            v.x = f2bf(acc[mi][ni][0] + bv);
            v.y = f2bf(acc[mi][ni][1] + bv);
            v.z = f2bf(acc[mi][ni][2] + bv);
            v.w = f2bf(acc[mi][ni][3] + bv);
            *(ushort4*)((unsigned short*)Cout3 +
                        ((size_t)bb * Dd + (c2 - Dd)) * Nn + np) = v;
          }
        }
      }
    }
  }
}

// ---------------------------------------------------------------------------
// gate2: logits -> softmax -> top-12 -> gates; block stats -> bstats.
// Also preps each token's xeg row (zero-fill + dense-gate cols) for the
// scatter-free pipeline.
// ---------------------------------------------------------------------------
__global__ __launch_bounds__(256) void gate2_kernel(
    const float* __restrict__ partial,
    int* __restrict__ idx, float* __restrict__ gate, float* __restrict__ bstats,
    unsigned short* __restrict__ xeg)
{
  __shared__ float xls[4][KS * Ee];
  __shared__ float sacc[49];
  __shared__ unsigned short dens[4][64];
  const int tid = threadIdx.x;
  const int w = tid >> 6, lane = tid & 63;
  const int t = blockIdx.x * 4 + w;

  if (tid < 49) sacc[tid] = 0.f;
  dens[w][lane] = 0;

  const float* p = partial + (size_t)t * (KS * Ee);
  #pragma unroll
  for (int i = 0; i < 6; ++i) xls[w][lane + i * 64] = p[lane + i * 64];

  // zero-fill xeg cols [0,1536) for this token (3 x ushort8 per lane)
  {
    u16x8 z = (u16x8){0, 0, 0, 0, 0, 0, 0, 0};
    unsigned short* xrow = xeg + (size_t)t * KR;
    #pragma unroll
    for (int i = 0; i < 3; ++i)
      *(u16x8*)&xrow[(lane + i * 64) * 8] = z;
  }

  float logit = -1e30f;
  if (lane < Ee) {
    float acc = 0.f;
    #pragma unroll
    for (int s = 0; s < KS; ++s) acc += xls[w][s * Ee + lane];
    logit = acc;
  }
  float m = logit;
  for (int o = 32; o; o >>= 1) m = fmaxf(m, __shfl_xor(m, o));
  float pr = (lane < Ee) ? expf(logit - m) : 0.f;
  float s = pr;
  for (int o = 32; o; o >>= 1) s += __shfl_xor(s, o);
  float prob = pr / s;
  float lse = m + logf(s);

  bool sel = false;
  float my_p = 0.f; int my_e = -1;
  for (int h = 0; h < Hh; ++h) {
    float v = (lane < Ee && !sel) ? prob : -1.f;
    int ix = lane;
    for (int o = 32; o; o >>= 1) {
      float ov = __shfl_xor(v, o); int oi = __shfl_xor(ix, o);
      if (ov > v || (ov == v && oi < ix)) { v = ov; ix = oi; }
    }
    if (lane == ix) sel = true;
    if (lane == h) { my_p = v; my_e = ix; }
  }
  float gsum = (lane < Hh) ? my_p : 0.f;
  for (int o = 32; o; o >>= 1) gsum += __shfl_xor(gsum, o);
  float gval = my_p / (gsum + 1e-6f);
  if (lane < Hh) {
    idx[t * Hh + lane] = my_e;
    gate[t * Hh + lane] = gval;
  }

  __syncthreads();
  if (lane < Ee) atomicAdd(&sacc[lane], prob);
  if (lane < Hh) {
    atomicAdd(&sacc[24 + my_e], 1.0f);
    dens[w][my_e] = f2bf(gval);
  }
  if (lane == 0) atomicAdd(&sacc[48], lse * lse);
  __syncthreads();
  if (tid < 49) bstats[(size_t)tid * NB2 + blockIdx.x] = sacc[tid];

  // dense-gate + pad cols [1536,1600): one short per lane
  xeg[(size_t)t * KR + 1536 + lane] = dens[w][lane];
}

// ---------------------------------------------------------------------------
// Flash attention with FUSED combine epilogue (R10 win config — unchanged).
// Core loop: transposed, 16 q/wave, in-register P, PV at K=32, 3-deep
// rotating LDS buffers (48 KB), 2-tile prefetch, counted vmcnt(8).
// Epilogue writes f2bf(gate * o / l) straight into xeg.
// ---------------------------------------------------------------------------
__global__ __launch_bounds__(256, 3) void attn_kernel(
    const unsigned short* __restrict__ qallb, const int* __restrict__ idx,
    const float* __restrict__ gate,
    const unsigned short* __restrict__ kbuf, const unsigned short* __restrict__ vtbuf,
    unsigned short* __restrict__ xeg)
{
  __shared__ __align__(16) unsigned short ksl[3][64 * 64];  // K tiles [key][d], swizzled
  __shared__ __align__(16) unsigned short vtl[3][64 * 64];  // V^T tiles [d][key-perm]

  const int tid = threadIdx.x;
  const int w = tid >> 6, lane = tid & 63;
  const int quad = lane >> 4, nl = lane & 15;
  const int bh = blockIdx.y;
  const int b = bh / Hh, h = bh - b * Hh;
  const int qw = blockIdx.x * 64 + w * 16;      // wave's 16 queries

  // Q B-frags (gathered via expert idx; pre-scaled by SCL at GEMM epilogue)
  const int tq = b * Nn + qw + nl;
  const int eq = idx[tq * Hh + h];
  const unsigned short* qrow = qallb + (size_t)tq * (Ee * Dd) + eq * Dd + quad * 8;
  const bf16x8 qB0 = *(const bf16x8*)(qrow);
  const bf16x8 qB1 = *(const bf16x8*)(qrow + 32);

  f32x4 acc[4];
  #pragma unroll
  for (int dg = 0; dg < 4; ++dg) acc[dg] = (f32x4){0.f, 0.f, 0.f, 0.f};
  float l = 0.f;

  const int sr  = lane >> 3;
  const int cbd = (lane & 7) ^ sr;              // XOR-swizzled source chunk
  const int xl  = nl & 7;
  const int ca0 = (quad ^ xl) * 8;              // b128 chunk offsets (K and V)
  const int ca1 = ((quad + 4) ^ xl) * 8;

  // wave-level staging bases (each wave stages rows w*16..w*16+15 of a tile)
  const unsigned short* kgbase =
      kbuf + ((size_t)b * Nn + w * 16 + sr) * Dd + cbd * 8;
  const unsigned short* vgbase =
      vtbuf + ((size_t)b * Dd + w * 16 + sr) * Nn + cbd * 8;

  auto STAGE = [&](int bi, int t) {
    const int j0 = t * 64;
    #pragma unroll
    for (int i = 0; i < 2; ++i) {
      gload16(kgbase + (size_t)(j0 + i * 8) * Dd, &ksl[bi][(w * 16 + i * 8) * 64]);
      gload16(vgbase + (size_t)(i * 8) * Nn + j0, &vtl[bi][(w * 16 + i * 8) * 64]);
    }
  };

  auto COMPUTE = [&](const unsigned short* ks_, const unsigned short* vt_) {
    __builtin_amdgcn_s_setprio(1);
    // --- S^T = K·Q^T ---
    bf16x4 pf[4];
    #pragma unroll
    for (int kg = 0; kg < 4; ++kg) {
      const unsigned short* kr = ks_ + (kg * 16 + nl) * 64;
      bf16x8 a0 = *(const bf16x8*)(kr + ca0);
      bf16x8 a1 = *(const bf16x8*)(kr + ca1);
      f32x4 c = {0.f, 0.f, 0.f, 0.f};
      c = __builtin_amdgcn_mfma_f32_16x16x32_bf16(a0, qB0, c, 0, 0, 0);
      c = __builtin_amdgcn_mfma_f32_16x16x32_bf16(a1, qB1, c, 0, 0, 0);
      float p0 = __builtin_amdgcn_exp2f(c[0]);
      float p1 = __builtin_amdgcn_exp2f(c[1]);
      float p2 = __builtin_amdgcn_exp2f(c[2]);
      float p3 = __builtin_amdgcn_exp2f(c[3]);
      l += (p0 + p1) + (p2 + p3);
      union { __hip_bfloat162 h2[2]; bf16x4 v; } pk;
      pk.h2[0] = __float22bfloat162_rn(float2{p0, p1});
      pk.h2[1] = __float22bfloat162_rn(float2{p2, p3});
      pf[kg] = pk.v;
    }
    bf16x8 pb0 = __builtin_shufflevector(pf[0], pf[1], 0, 1, 2, 3, 4, 5, 6, 7);
    bf16x8 pb1 = __builtin_shufflevector(pf[2], pf[3], 0, 1, 2, 3, 4, 5, 6, 7);
    // --- O^T += V^T·P^T at K=32 ---
    #pragma unroll
    for (int dg = 0; dg < 4; ++dg) {
      const unsigned short* vrow = vt_ + (dg * 16 + nl) * 64;
      bf16x8 v0 = *(const bf16x8*)(vrow + ca0);
      bf16x8 v1 = *(const bf16x8*)(vrow + ca1);
      acc[dg] = __builtin_amdgcn_mfma_f32_16x16x32_bf16(v0, pb0, acc[dg], 0, 0, 0);
      acc[dg] = __builtin_amdgcn_mfma_f32_16x16x32_bf16(v1, pb1, acc[dg], 0, 0, 0);
    }
    __builtin_amdgcn_s_setprio(0);
  };

  // ---- software pipeline: 32 tiles, 2-deep prefetch, 3 rotating buffers ----
  STAGE(0, 0);
  STAGE(1, 1);
  #pragma unroll 1
  for (int t = 0; t < 30; t += 3) {
    STAGE(2, t + 2);
    asm volatile("s_waitcnt vmcnt(8)" ::: "memory");
    __builtin_amdgcn_s_barrier();
    __builtin_amdgcn_sched_barrier(0);
    COMPUTE(ksl[0], vtl[0]);
    __builtin_amdgcn_sched_barrier(0);
    asm volatile("" ::: "memory");
    __builtin_amdgcn_s_barrier();

    STAGE(0, t + 3);
    asm volatile("s_waitcnt vmcnt(8)" ::: "memory");
    __builtin_amdgcn_s_barrier();
    __builtin_amdgcn_sched_barrier(0);
    COMPUTE(ksl[1], vtl[1]);
    __builtin_amdgcn_sched_barrier(0);
    asm volatile("" ::: "memory");
    __builtin_amdgcn_s_barrier();

    STAGE(1, t + 4);
    asm volatile("s_waitcnt vmcnt(8)" ::: "memory");
    __builtin_amdgcn_s_barrier();
    __builtin_amdgcn_sched_barrier(0);
    COMPUTE(ksl[2], vtl[2]);
    __builtin_amdgcn_sched_barrier(0);
    asm volatile("" ::: "memory");
    __builtin_amdgcn_s_barrier();
  }
  asm volatile("s_waitcnt vmcnt(4)" ::: "memory");
  __builtin_amdgcn_s_barrier();
  __builtin_amdgcn_sched_barrier(0);
  COMPUTE(ksl[0], vtl[0]);
  __builtin_amdgcn_sched_barrier(0);
  asm volatile("s_waitcnt vmcnt(0)" ::: "memory");
  __builtin_amdgcn_s_barrier();
  __builtin_amdgcn_sched_barrier(0);
  COMPUTE(ksl[1], vtl[1]);

  // ---- fused combine epilogue: xeg[tq][eq*64 + d] = f2bf(gate * o / l) ----
  float lg = l;
  lg += __shfl_xor(lg, 16);
  lg += __shfl_xor(lg, 32);                      // full softmax sum for query nl
  const float scale = gate[tq * Hh + h] / lg;
  unsigned short* xrow = xeg + (size_t)tq * KR + eq * Dd + quad * 4;
  #pragma unroll
  for (int dg = 0; dg < 4; ++dg) {
    ushort4 v;
    v.x = f2bf(acc[dg][0] * scale);
    v.y = f2bf(acc[dg][1] * scale);
    v.z = f2bf(acc[dg][2] * scale);
    v.w = f2bf(acc[dg][3] * scale);
    *(ushort4*)(xrow + dg * 16) = v;
  }
}

// ---------------------------------------------------------------------------
// aux1: parallel bstats row-sum -> stats2[49];  aux2: finalize
// ---------------------------------------------------------------------------
__global__ __launch_bounds__(256) void aux1_kernel(
    const float* __restrict__ bstats, float* __restrict__ stats2)
{
  __shared__ float r[4];
  const int j = blockIdx.x, tid = threadIdx.x;
  float4 v = *(const float4*)&bstats[(size_t)j * NB2 + tid * 4];
  float s = (v.x + v.y) + (v.z + v.w);
  for (int o = 32; o; o >>= 1) s += __shfl_xor(s, o);
  if ((tid & 63) == 0) r[tid >> 6] = s;
  __syncthreads();
  if (tid == 0) stats2[j] = (r[0] + r[1]) + (r[2] + r[3]);
}

__global__ void aux2_kernel(const float* __restrict__ stats2,
                            float* __restrict__ out, int out_size)
{
  const int lane = threadIdx.x;
  float a = (lane < Ee) ? stats2[lane] : 0.f;
  float b = (lane < Ee) ? stats2[24 + lane] : 0.f;
  float pt = a, ft = b, sw = a * b;
  for (int o = 32; o; o >>= 1) {
    pt += __shfl_xor(pt, o); ft += __shfl_xor(ft, o); sw += __shfl_xor(sw, o);
  }
  if (lane == 0) {
    float sswitch = (float)Ee * sw / (pt * ft);
    float z = stats2[48] * (1.0f / (float)T_);
    out[out_size - 1] = 0.1f * sswitch + 0.001f * z;
  }
}

// ---------------------------------------------------------------------------
extern "C" void kernel_launch(void* const* d_in, const int* in_sizes, int n_in,
                              void* d_out, int out_size, void* d_ws, size_t ws_size,
                              hipStream_t stream)
{
  const float* x     = (const float*)d_in[0];
  const float* wg    = (const float*)d_in[1];
  const float* W_in  = (const float*)d_in[2];
  const float* b_in  = (const float*)d_in[3];
  const float* W_out = (const float*)d_in[4];
  const float* b_out = (const float*)d_in[5];
  const float* W_kv  = (const float*)d_in[6];
  const float* b_kv  = (const float*)d_in[7];
  float* out = (float*)d_out;

  char* ws = (char*)d_ws;
  size_t off = 0;
  auto carve = [&](size_t bytes) -> void* {
    void* p = ws + off;
    off = (off + bytes + 255) & ~(size_t)255;
    return p;
  };
  int*            idx    = (int*)           carve((size_t)T_ * Hh * 4);
  float*          gate   = (float*)         carve((size_t)T_ * Hh * 4);
  float*          bstats = (float*)         carve((size_t)49 * NB2 * 4);
  float*          stats2 = (float*)         carve(256);
  float*          lgate  = (float*)         carve((size_t)T_ * KS * Ee * 4);
  unsigned short* xb     = (unsigned short*)carve((size_t)T_ * Cc * 2);
  unsigned short* BqkvT  = (unsigned short*)carve((size_t)(Ee * Dd + 128) * Cc * 2);
  unsigned short* BkvT   = BqkvT + (size_t)Ee * Dd * Cc;
  unsigned short* BrT    = (unsigned short*)carve((size_t)Cc * KR * 2);
  unsigned short* kbuf   = (unsigned short*)carve((size_t)T_ * Dd * 2);
  unsigned short* vtbuf  = (unsigned short*)carve((size_t)T_ * Dd * 2);
  unsigned short* qallb  = (unsigned short*)carve((size_t)T_ * Ee * Dd * 2);
  unsigned short* xeg    = (unsigned short*)carve((size_t)T_ * KR * 2);

  // merged weight conversion + gate1 (occupancy-fixed: 33 KB LDS, 1412 blocks)
  prep_kernel<<<1412, 256, 0, stream>>>(
      W_in, W_out, b_out, W_kv, BqkvT, BrT, BkvT, x, wg, lgate, xb);

  // gate2 (softmax/top-k/stats + xeg row prep)
  gate2_kernel<<<NB2, 256, 0, stream>>>(lgate, idx, gate, bstats, xeg);

  // fused qall + kv GEMM: 64x64 tiles, BK=64, grid (64, 26)
  gemm_bt_kernel<1><<<dim3(T_ / 64, 26), 256, 0, stream>>>(
      xb, BqkvT, b_in, b_kv, qallb, kbuf, vtbuf, Cc, 1536);

  // attention with fused combine epilogue -> xeg
  attn_kernel<<<dim3(Nn / 64, Bb * Hh), 256, 0, stream>>>(
      qallb, idx, gate, kbuf, vtbuf, xeg);

  // out = xeg @ BrT^T -> f32: 64x64 tiles, BK=64, grid (64, 12)
  gemm_bt_kernel<0><<<dim3(T_ / 64, Cc / 64), 256, 0, stream>>>(
      xeg, BrT, nullptr, nullptr, out, nullptr, nullptr, KR, Cc);

  // aux loss
  aux1_kernel<<<49, 256, 0, stream>>>(bstats, stats2);
  aux2_kernel<<<1, 64, 0, stream>>>(stats2, out, out_size);
}

// Round 14
// 177.332 us; speedup vs baseline: 1.0896x; 1.0128x over previous
//
#include <hip/hip_runtime.h>
#include <hip/hip_bf16.h>

// Problem constants
#define T_  4096
#define Bb  2
#define Nn  2048
#define Cc  768
#define Ee  24
#define Dd  64
#define Hh  12
#define KR  1600   // reduce GEMM K: 1536 (W_out) + 24 (b_out) + 40 pad (mult of 64)
#define KS  16     // gate k-split
#define KC  48     // 768 / KS
#define NB2 1024   // gate2 block count (T_/4)
#define SCL 0.18033688f   // 0.125 * log2(e) — folded into q at GEMM epilogue

typedef __attribute__((ext_vector_type(8))) short bf16x8;
typedef __attribute__((ext_vector_type(4))) short bf16x4;
typedef __attribute__((ext_vector_type(4))) float f32x4;
typedef __attribute__((ext_vector_type(8))) unsigned short u16x8;

__device__ __forceinline__ unsigned short f2bf(float f) {
  union { float f; unsigned int i; } u; u.f = f;
  unsigned int r = u.i + 0x7FFFu + ((u.i >> 16) & 1u);
  return (unsigned short)(r >> 16);
}

__device__ __forceinline__ void gload16(const void* g, void* l) {
  __builtin_amdgcn_global_load_lds(
      (const __attribute__((address_space(1))) void*)g,
      (__attribute__((address_space(3))) void*)l, 16, 0, 0);
}

// ---------------------------------------------------------------------------
// MERGED prep kernel (R13 win config — unchanged): weight conversion + gate1.
//   blocks [0,288)     : W_in -> BqT
//   blocks [288,888)   : [W_out;b_out;pad] -> BrT
//   blocks [888,900)   : W_kv -> BkvT
//   blocks [900,1412)  : gate1 (512 blocks: 32 t-chunks x 16 k-slices)
// ---------------------------------------------------------------------------
#define XPAD 52
__global__ __launch_bounds__(256) void prep_kernel(
    const float* __restrict__ W_in, const float* __restrict__ W_out,
    const float* __restrict__ b_out, const float* __restrict__ W_kv,
    unsigned short* __restrict__ BqT, unsigned short* __restrict__ BrT,
    unsigned short* __restrict__ BkvT,
    const float* __restrict__ x, const float* __restrict__ wg,
    float* __restrict__ partial, unsigned short* __restrict__ xb)
{
  __shared__ __align__(16) float smem[64 * 129];   // 33 KB (max of both uses)
  const int bid = blockIdx.x, tid = threadIdx.x;

  if (bid < 900) {
    float* ls = smem;
    if (bid < 288) {
      const int e = bid / 12, c0 = (bid % 12) * 64;
      #pragma unroll
      for (int i = 0; i < 16; ++i) {
        int L = tid + i * 256, c = L >> 6, d = L & 63;
        ls[c * 65 + d] = W_in[(size_t)e * Cc * Dd + (size_t)(c0 + c) * Dd + d];
      }
      __syncthreads();
      #pragma unroll
      for (int i = 0; i < 16; ++i) {
        int L = tid + i * 256, d = L >> 6, c = L & 63;
        BqT[(size_t)(e * Dd + d) * Cc + c0 + c] = f2bf(ls[c * 65 + d]);
      }
    } else if (bid < 888) {
      const int i2 = bid - 288;
      const int k0 = (i2 / 12) * 32, n0 = (i2 % 12) * 64;
      #pragma unroll
      for (int i = 0; i < 8; ++i) {
        int L = tid + i * 256, k = L >> 6, n = L & 63;
        int kk = k0 + k;
        float v = (kk < 1536) ? W_out[(size_t)kk * Cc + n0 + n]
                : (kk < 1560) ? b_out[(size_t)(kk - 1536) * Cc + n0 + n] : 0.f;
        ls[k * 65 + n] = v;
      }
      __syncthreads();
      #pragma unroll
      for (int i = 0; i < 8; ++i) {
        int L = tid + i * 256, n = L >> 5, k = L & 31;
        BrT[(size_t)(n0 + n) * KR + k0 + k] = f2bf(ls[k * 65 + n]);
      }
    } else {
      const int c0 = (bid - 888) * 64;
      #pragma unroll
      for (int i = 0; i < 32; ++i) {
        int L = tid + i * 256, c = L >> 7, j = L & 127;
        ls[c * 129 + j] = W_kv[(size_t)(c0 + c) * 128 + j];
      }
      __syncthreads();
      #pragma unroll
      for (int i = 0; i < 32; ++i) {
        int L = tid + i * 256, j = L >> 6, c = L & 63;
        BkvT[(size_t)j * Cc + c0 + c] = f2bf(ls[c * 129 + j]);
      }
    }
  } else {
    // ---- gate1: 128 tokens/block, 2 threads per token ----
    float* xs  = smem;                 // 128 * XPAD floats
    float* wsT = smem + 128 * XPAD;    // Ee * KC floats
    const int g = bid - 900;
    const int t0 = (g & 31) * 128;
    const int s = g >> 5, k0 = s * KC;

    #pragma unroll
    for (int i = 0; i < 6; ++i) {
      int f = tid + i * 256;
      int token = f / 12, j = f % 12;
      size_t gofs = (size_t)(t0 + token) * Cc + k0 + j * 4;
      float4 v = *(const float4*)&x[gofs];
      *(float4*)&xs[token * XPAD + j * 4] = v;
      ushort4 o;
      o.x = f2bf(v.x); o.y = f2bf(v.y); o.z = f2bf(v.z); o.w = f2bf(v.w);
      *(ushort4*)&xb[gofs] = o;
    }
    for (int i = tid; i < Ee * KC; i += 256)
      wsT[(i % Ee) * KC + i / Ee] = wg[k0 * Ee + i];
    __syncthreads();

    const int token = tid >> 1, half = tid & 1;
    float xr[KC];
    #pragma unroll
    for (int kg = 0; kg < KC / 4; ++kg)
      *(float4*)&xr[kg * 4] = *(const float4*)&xs[token * XPAD + kg * 4];

    float acc[12];
    #pragma unroll
    for (int e = 0; e < 12; ++e) acc[e] = 0.f;
    #pragma unroll
    for (int e = 0; e < 12; ++e) {
      const int eg = half * 12 + e;
      #pragma unroll
      for (int kg = 0; kg < KC / 4; ++kg) {
        float4 wv = *(const float4*)&wsT[eg * KC + kg * 4];
        acc[e] += xr[kg * 4 + 0] * wv.x + xr[kg * 4 + 1] * wv.y
                + xr[kg * 4 + 2] * wv.z + xr[kg * 4 + 3] * wv.w;
      }
    }

    float* dst = partial + ((size_t)(t0 + token) * KS + s) * Ee + half * 12;
    #pragma unroll
    for (int eg2 = 0; eg2 < 3; ++eg2)
      *(float4*)&dst[eg2 * 4] = *(float4*)&acc[eg2 * 4];
  }
}

// ---------------------------------------------------------------------------
// Shared 64x64 BK=64 GEMM body (R9/R10 validated structure): 2-phase double
// buffer, attn-style XOR-swizzled staging/reads (zero bank conflicts).
// AsB/BsB point into the caller's 32 KB LDS (2 x 4096 shorts each).
// MODE 0: f32 out (reduce).  MODE 1: fused qall+kv epilogue.
// ---------------------------------------------------------------------------
template<int MODE>
__device__ __forceinline__ void gemm64_body(
    int m0, int n0, unsigned short* AsB, unsigned short* BsB,
    const unsigned short* __restrict__ A, const unsigned short* __restrict__ BT,
    const float* __restrict__ bias, const float* __restrict__ bias2,
    void* __restrict__ Cout, void* __restrict__ Cout2, void* __restrict__ Cout3,
    int K, int ldc)
{
  constexpr int MI = 2, NI = 2;
  const int tid = threadIdx.x, w = tid >> 6, lane = tid & 63;
  const int quad = lane >> 4, nl = lane & 15;
  const int mw = (w & 1) * 32, nw = (w >> 1) * 32;

  f32x4 acc[MI][NI];
  #pragma unroll
  for (int i = 0; i < MI; ++i)
    #pragma unroll
    for (int j = 0; j < NI; ++j) acc[i][j] = (f32x4){0.f, 0.f, 0.f, 0.f};

  const int sr  = lane >> 3;
  const int cbd = (lane & 7) ^ sr;
  const int xl  = nl & 7;
  const int ca0 = (quad ^ xl) * 8;
  const int ca1 = ((quad + 4) ^ xl) * 8;

  const unsigned short* abase = A + (size_t)(m0 + w * 16 + sr) * K + cbd * 8;
  const unsigned short* bbase = BT + (size_t)(n0 + w * 16 + sr) * K + cbd * 8;

  auto STAGE = [&](int bi, int k0) {
    #pragma unroll
    for (int i = 0; i < 2; ++i) {
      gload16(abase + (size_t)(i * 8) * K + k0, AsB + bi * 4096 + (w * 16 + i * 8) * 64);
      gload16(bbase + (size_t)(i * 8) * K + k0, BsB + bi * 4096 + (w * 16 + i * 8) * 64);
    }
  };

  const int nt = K / 64;
  STAGE(0, 0);
  __syncthreads();
  for (int t = 0; t < nt; ++t) {
    const int cur = t & 1;
    if (t + 1 < nt) STAGE(cur ^ 1, (t + 1) * 64);   // issue next BEFORE compute

    const unsigned short* Ac = AsB + cur * 4096;
    const unsigned short* Bc = BsB + cur * 4096;
    bf16x8 af0[MI], af1[MI], bf0[NI], bf1[NI];
    #pragma unroll
    for (int mi = 0; mi < MI; ++mi) {
      const unsigned short* ar = &Ac[(mw + mi * 16 + nl) * 64];
      af0[mi] = *(const bf16x8*)(ar + ca0);
      af1[mi] = *(const bf16x8*)(ar + ca1);
    }
    #pragma unroll
    for (int ni = 0; ni < NI; ++ni) {
      const unsigned short* br = &Bc[(nw + ni * 16 + nl) * 64];
      bf0[ni] = *(const bf16x8*)(br + ca0);
      bf1[ni] = *(const bf16x8*)(br + ca1);
    }
    #pragma unroll
    for (int mi = 0; mi < MI; ++mi)
      #pragma unroll
      for (int ni = 0; ni < NI; ++ni) {
        acc[mi][ni] = __builtin_amdgcn_mfma_f32_16x16x32_bf16(
            af0[mi], bf0[ni], acc[mi][ni], 0, 0, 0);
        acc[mi][ni] = __builtin_amdgcn_mfma_f32_16x16x32_bf16(
            af1[mi], bf1[ni], acc[mi][ni], 0, 0, 0);
      }

    __syncthreads();
  }

  #pragma unroll
  for (int mi = 0; mi < MI; ++mi) {
    int rowb = m0 + mw + mi * 16 + quad * 4;
    int bb = rowb >> 11, nn = rowb & (Nn - 1);
    #pragma unroll
    for (int ni = 0; ni < NI; ++ni) {
      int col = n0 + nw + ni * 16 + nl;
      if (MODE == 0) {
        #pragma unroll
        for (int reg = 0; reg < 4; ++reg)
          ((float*)Cout)[(size_t)(rowb + reg) * ldc + col] = acc[mi][ni][reg];
      } else {
        if (col < 1536) {
          float bv = bias[col];
          #pragma unroll
          for (int reg = 0; reg < 4; ++reg)
            ((unsigned short*)Cout)[(size_t)(rowb + reg) * 1536 + col] =
                f2bf((acc[mi][ni][reg] + bv) * SCL);
        } else {
          int c2 = col - 1536;
          float bv = bias2[c2];
          if (c2 < Dd) {
            #pragma unroll
            for (int reg = 0; reg < 4; ++reg)
              ((unsigned short*)Cout2)[((size_t)bb * Nn + nn + reg) * Dd + c2] =
                  f2bf(acc[mi][ni][reg] + bv);
          } else {
            int p6 = nn & 63;
            int np = (nn & ~63) | (p6 & 0x23)
                   | (((p6 >> 4) & 1) << 2) | (((p6 >> 2) & 3) << 3);
            ushort4 v;
            v.x = f2bf(acc[mi][ni][0] + bv);
            v.y = f2bf(acc[mi][ni][1] + bv);
            v.z = f2bf(acc[mi][ni][2] + bv);
            v.w = f2bf(acc[mi][ni][3] + bv);
            *(ushort4*)((unsigned short*)Cout3 +
                        ((size_t)bb * Dd + (c2 - Dd)) * Nn + np) = v;
          }
        }
      }
    }
  }
}

// ---------------------------------------------------------------------------
// MERGED gate2 + qkv GEMM (independent work, one dispatch; both hidden under
// the other's latency).  LDS = single 32 KB buffer (the GEMM's footprint —
// occupancy of GEMM blocks unchanged; gate2 needs only ~7 KB, aliased).
//   blocks [0,1024)      : gate2 (softmax/top-k/stats + xeg row prep)
//   blocks [1024,2688)   : qkv GEMM, m-fastest decode (preserves old order)
// ---------------------------------------------------------------------------
__global__ __launch_bounds__(256) void qkv_gate2_kernel(
    const unsigned short* __restrict__ xb, const unsigned short* __restrict__ BqkvT,
    const float* __restrict__ b_in, const float* __restrict__ b_kv,
    unsigned short* __restrict__ qallb, unsigned short* __restrict__ kbuf,
    unsigned short* __restrict__ vtbuf,
    const float* __restrict__ partial, int* __restrict__ idx,
    float* __restrict__ gate, float* __restrict__ bstats,
    unsigned short* __restrict__ xeg)
{
  __shared__ __align__(16) char smem[65536 / 2];   // 32 KB
  const int bid = blockIdx.x, tid = threadIdx.x;

  if (bid >= NB2) {
    const int b2 = bid - NB2;
    const int m0 = (b2 & 63) * 64, n0 = (b2 >> 6) * 64;
    gemm64_body<1>(m0, n0, (unsigned short*)smem, (unsigned short*)smem + 8192,
                   xb, BqkvT, b_in, b_kv, qallb, kbuf, vtbuf, Cc, 1536);
    return;
  }

  // ---- gate2 ----
  float* xls  = (float*)smem;                       // [4][KS*Ee] = 1536 f
  float* sacc = xls + 4 * KS * Ee;                  // 49 f (pad to 64)
  unsigned short* dens = (unsigned short*)(sacc + 64);  // [4][64]
  const int w = tid >> 6, lane = tid & 63;
  const int t = bid * 4 + w;

  if (tid < 49) sacc[tid] = 0.f;
  dens[w * 64 + lane] = 0;

  const float* p = partial + (size_t)t * (KS * Ee);
  #pragma unroll
  for (int i = 0; i < 6; ++i) xls[w * (KS * Ee) + lane + i * 64] = p[lane + i * 64];

  // zero-fill xeg cols [0,1536) for this token (3 x ushort8 per lane)
  {
    u16x8 z = (u16x8){0, 0, 0, 0, 0, 0, 0, 0};
    unsigned short* xrow = xeg + (size_t)t * KR;
    #pragma unroll
    for (int i = 0; i < 3; ++i)
      *(u16x8*)&xrow[(lane + i * 64) * 8] = z;
  }

  float logit = -1e30f;
  if (lane < Ee) {
    float acc = 0.f;
    #pragma unroll
    for (int s = 0; s < KS; ++s) acc += xls[w * (KS * Ee) + s * Ee + lane];
    logit = acc;
  }
  float m = logit;
  for (int o = 32; o; o >>= 1) m = fmaxf(m, __shfl_xor(m, o));
  float pr = (lane < Ee) ? expf(logit - m) : 0.f;
  float s = pr;
  for (int o = 32; o; o >>= 1) s += __shfl_xor(s, o);
  float prob = pr / s;
  float lse = m + logf(s);

  bool sel = false;
  float my_p = 0.f; int my_e = -1;
  for (int h = 0; h < Hh; ++h) {
    float v = (lane < Ee && !sel) ? prob : -1.f;
    int ix = lane;
    for (int o = 32; o; o >>= 1) {
      float ov = __shfl_xor(v, o); int oi = __shfl_xor(ix, o);
      if (ov > v || (ov == v && oi < ix)) { v = ov; ix = oi; }
    }
    if (lane == ix) sel = true;
    if (lane == h) { my_p = v; my_e = ix; }
  }
  float gsum = (lane < Hh) ? my_p : 0.f;
  for (int o = 32; o; o >>= 1) gsum += __shfl_xor(gsum, o);
  float gval = my_p / (gsum + 1e-6f);
  if (lane < Hh) {
    idx[t * Hh + lane] = my_e;
    gate[t * Hh + lane] = gval;
  }

  __syncthreads();
  if (lane < Ee) atomicAdd(&sacc[lane], prob);
  if (lane < Hh) {
    atomicAdd(&sacc[24 + my_e], 1.0f);
    dens[w * 64 + my_e] = f2bf(gval);
  }
  if (lane == 0) atomicAdd(&sacc[48], lse * lse);
  __syncthreads();
  if (tid < 49) bstats[(size_t)tid * NB2 + bid] = sacc[tid];

  // dense-gate + pad cols [1536,1600): one short per lane
  xeg[(size_t)t * KR + 1536 + lane] = dens[w * 64 + lane];
}

// ---------------------------------------------------------------------------
// Flash attention with FUSED combine epilogue (R10 win config — unchanged).
// ---------------------------------------------------------------------------
__global__ __launch_bounds__(256, 3) void attn_kernel(
    const unsigned short* __restrict__ qallb, const int* __restrict__ idx,
    const float* __restrict__ gate,
    const unsigned short* __restrict__ kbuf, const unsigned short* __restrict__ vtbuf,
    unsigned short* __restrict__ xeg)
{
  __shared__ __align__(16) unsigned short ksl[3][64 * 64];  // K tiles [key][d], swizzled
  __shared__ __align__(16) unsigned short vtl[3][64 * 64];  // V^T tiles [d][key-perm]

  const int tid = threadIdx.x;
  const int w = tid >> 6, lane = tid & 63;
  const int quad = lane >> 4, nl = lane & 15;
  const int bh = blockIdx.y;
  const int b = bh / Hh, h = bh - b * Hh;
  const int qw = blockIdx.x * 64 + w * 16;      // wave's 16 queries

  const int tq = b * Nn + qw + nl;
  const int eq = idx[tq * Hh + h];
  const unsigned short* qrow = qallb + (size_t)tq * (Ee * Dd) + eq * Dd + quad * 8;
  const bf16x8 qB0 = *(const bf16x8*)(qrow);
  const bf16x8 qB1 = *(const bf16x8*)(qrow + 32);

  f32x4 acc[4];
  #pragma unroll
  for (int dg = 0; dg < 4; ++dg) acc[dg] = (f32x4){0.f, 0.f, 0.f, 0.f};
  float l = 0.f;

  const int sr  = lane >> 3;
  const int cbd = (lane & 7) ^ sr;              // XOR-swizzled source chunk
  const int xl  = nl & 7;
  const int ca0 = (quad ^ xl) * 8;              // b128 chunk offsets (K and V)
  const int ca1 = ((quad + 4) ^ xl) * 8;

  const unsigned short* kgbase =
      kbuf + ((size_t)b * Nn + w * 16 + sr) * Dd + cbd * 8;
  const unsigned short* vgbase =
      vtbuf + ((size_t)b * Dd + w * 16 + sr) * Nn + cbd * 8;

  auto STAGE = [&](int bi, int t) {
    const int j0 = t * 64;
    #pragma unroll
    for (int i = 0; i < 2; ++i) {
      gload16(kgbase + (size_t)(j0 + i * 8) * Dd, &ksl[bi][(w * 16 + i * 8) * 64]);
      gload16(vgbase + (size_t)(i * 8) * Nn + j0, &vtl[bi][(w * 16 + i * 8) * 64]);
    }
  };

  auto COMPUTE = [&](const unsigned short* ks_, const unsigned short* vt_) {
    __builtin_amdgcn_s_setprio(1);
    bf16x4 pf[4];
    #pragma unroll
    for (int kg = 0; kg < 4; ++kg) {
      const unsigned short* kr = ks_ + (kg * 16 + nl) * 64;
      bf16x8 a0 = *(const bf16x8*)(kr + ca0);
      bf16x8 a1 = *(const bf16x8*)(kr + ca1);
      f32x4 c = {0.f, 0.f, 0.f, 0.f};
      c = __builtin_amdgcn_mfma_f32_16x16x32_bf16(a0, qB0, c, 0, 0, 0);
      c = __builtin_amdgcn_mfma_f32_16x16x32_bf16(a1, qB1, c, 0, 0, 0);
      float p0 = __builtin_amdgcn_exp2f(c[0]);
      float p1 = __builtin_amdgcn_exp2f(c[1]);
      float p2 = __builtin_amdgcn_exp2f(c[2]);
      float p3 = __builtin_amdgcn_exp2f(c[3]);
      l += (p0 + p1) + (p2 + p3);
      union { __hip_bfloat162 h2[2]; bf16x4 v; } pk;
      pk.h2[0] = __float22bfloat162_rn(float2{p0, p1});
      pk.h2[1] = __float22bfloat162_rn(float2{p2, p3});
      pf[kg] = pk.v;
    }
    bf16x8 pb0 = __builtin_shufflevector(pf[0], pf[1], 0, 1, 2, 3, 4, 5, 6, 7);
    bf16x8 pb1 = __builtin_shufflevector(pf[2], pf[3], 0, 1, 2, 3, 4, 5, 6, 7);
    #pragma unroll
    for (int dg = 0; dg < 4; ++dg) {
      const unsigned short* vrow = vt_ + (dg * 16 + nl) * 64;
      bf16x8 v0 = *(const bf16x8*)(vrow + ca0);
      bf16x8 v1 = *(const bf16x8*)(vrow + ca1);
      acc[dg] = __builtin_amdgcn_mfma_f32_16x16x32_bf16(v0, pb0, acc[dg], 0, 0, 0);
      acc[dg] = __builtin_amdgcn_mfma_f32_16x16x32_bf16(v1, pb1, acc[dg], 0, 0, 0);
    }
    __builtin_amdgcn_s_setprio(0);
  };

  STAGE(0, 0);
  STAGE(1, 1);
  #pragma unroll 1
  for (int t = 0; t < 30; t += 3) {
    STAGE(2, t + 2);
    asm volatile("s_waitcnt vmcnt(8)" ::: "memory");
    __builtin_amdgcn_s_barrier();
    __builtin_amdgcn_sched_barrier(0);
    COMPUTE(ksl[0], vtl[0]);
    __builtin_amdgcn_sched_barrier(0);
    asm volatile("" ::: "memory");
    __builtin_amdgcn_s_barrier();

    STAGE(0, t + 3);
    asm volatile("s_waitcnt vmcnt(8)" ::: "memory");
    __builtin_amdgcn_s_barrier();
    __builtin_amdgcn_sched_barrier(0);
    COMPUTE(ksl[1], vtl[1]);
    __builtin_amdgcn_sched_barrier(0);
    asm volatile("" ::: "memory");
    __builtin_amdgcn_s_barrier();

    STAGE(1, t + 4);
    asm volatile("s_waitcnt vmcnt(8)" ::: "memory");
    __builtin_amdgcn_s_barrier();
    __builtin_amdgcn_sched_barrier(0);
    COMPUTE(ksl[2], vtl[2]);
    __builtin_amdgcn_sched_barrier(0);
    asm volatile("" ::: "memory");
    __builtin_amdgcn_s_barrier();
  }
  asm volatile("s_waitcnt vmcnt(4)" ::: "memory");
  __builtin_amdgcn_s_barrier();
  __builtin_amdgcn_sched_barrier(0);
  COMPUTE(ksl[0], vtl[0]);
  __builtin_amdgcn_sched_barrier(0);
  asm volatile("s_waitcnt vmcnt(0)" ::: "memory");
  __builtin_amdgcn_s_barrier();
  __builtin_amdgcn_sched_barrier(0);
  COMPUTE(ksl[1], vtl[1]);

  // ---- fused combine epilogue: xeg[tq][eq*64 + d] = f2bf(gate * o / l) ----
  float lg = l;
  lg += __shfl_xor(lg, 16);
  lg += __shfl_xor(lg, 32);
  const float scale = gate[tq * Hh + h] / lg;
  unsigned short* xrow = xeg + (size_t)tq * KR + eq * Dd + quad * 4;
  #pragma unroll
  for (int dg = 0; dg < 4; ++dg) {
    ushort4 v;
    v.x = f2bf(acc[dg][0] * scale);
    v.y = f2bf(acc[dg][1] * scale);
    v.z = f2bf(acc[dg][2] * scale);
    v.w = f2bf(acc[dg][3] * scale);
    *(ushort4*)(xrow + dg * 16) = v;
  }
}

// ---------------------------------------------------------------------------
// MERGED reduce GEMM + aux1 (independent: aux1 reads bstats from gate2's
// dispatch).  Flat grid 768+49: [0,768) GEMM m-fastest; [768,817) aux1.
// ---------------------------------------------------------------------------
__global__ __launch_bounds__(256) void reduce_aux_kernel(
    const unsigned short* __restrict__ xeg, const unsigned short* __restrict__ BrT,
    float* __restrict__ out,
    const float* __restrict__ bstats, float* __restrict__ stats2)
{
  __shared__ __align__(16) char smem[65536 / 2];   // 32 KB
  const int bid = blockIdx.x, tid = threadIdx.x;

  if (bid >= 768) {
    // ---- aux1: bstats row-sum -> stats2[j] ----
    float* r = (float*)smem;
    const int j = bid - 768;
    float4 v = *(const float4*)&bstats[(size_t)j * NB2 + tid * 4];
    float s = (v.x + v.y) + (v.z + v.w);
    for (int o = 32; o; o >>= 1) s += __shfl_xor(s, o);
    if ((tid & 63) == 0) r[tid >> 6] = s;
    __syncthreads();
    if (tid == 0) stats2[j] = (r[0] + r[1]) + (r[2] + r[3]);
    return;
  }

  const int m0 = (bid & 63) * 64, n0 = (bid >> 6) * 64;
  gemm64_body<0>(m0, n0, (unsigned short*)smem, (unsigned short*)smem + 8192,
                 xeg, BrT, nullptr, nullptr, out, nullptr, nullptr, KR, Cc);
}

__global__ void aux2_kernel(const float* __restrict__ stats2,
                            float* __restrict__ out, int out_size)
{
  const int lane = threadIdx.x;
  float a = (lane < Ee) ? stats2[lane] : 0.f;
  float b = (lane < Ee) ? stats2[24 + lane] : 0.f;
  float pt = a, ft = b, sw = a * b;
  for (int o = 32; o; o >>= 1) {
    pt += __shfl_xor(pt, o); ft += __shfl_xor(ft, o); sw += __shfl_xor(sw, o);
  }
  if (lane == 0) {
    float sswitch = (float)Ee * sw / (pt * ft);
    float z = stats2[48] * (1.0f / (float)T_);
    out[out_size - 1] = 0.1f * sswitch + 0.001f * z;
  }
}

// ---------------------------------------------------------------------------
extern "C" void kernel_launch(void* const* d_in, const int* in_sizes, int n_in,
                              void* d_out, int out_size, void* d_ws, size_t ws_size,
                              hipStream_t stream)
{
  const float* x     = (const float*)d_in[0];
  const float* wg    = (const float*)d_in[1];
  const float* W_in  = (const float*)d_in[2];
  const float* b_in  = (const float*)d_in[3];
  const float* W_out = (const float*)d_in[4];
  const float* b_out = (const float*)d_in[5];
  const float* W_kv  = (const float*)d_in[6];
  const float* b_kv  = (const float*)d_in[7];
  float* out = (float*)d_out;

  char* ws = (char*)d_ws;
  size_t off = 0;
  auto carve = [&](size_t bytes) -> void* {
    void* p = ws + off;
    off = (off + bytes + 255) & ~(size_t)255;
    return p;
  };
  int*            idx    = (int*)           carve((size_t)T_ * Hh * 4);
  float*          gate   = (float*)         carve((size_t)T_ * Hh * 4);
  float*          bstats = (float*)         carve((size_t)49 * NB2 * 4);
  float*          stats2 = (float*)         carve(256);
  float*          lgate  = (float*)         carve((size_t)T_ * KS * Ee * 4);
  unsigned short* xb     = (unsigned short*)carve((size_t)T_ * Cc * 2);
  unsigned short* BqkvT  = (unsigned short*)carve((size_t)(Ee * Dd + 128) * Cc * 2);
  unsigned short* BkvT   = BqkvT + (size_t)Ee * Dd * Cc;
  unsigned short* BrT    = (unsigned short*)carve((size_t)Cc * KR * 2);
  unsigned short* kbuf   = (unsigned short*)carve((size_t)T_ * Dd * 2);
  unsigned short* vtbuf  = (unsigned short*)carve((size_t)T_ * Dd * 2);
  unsigned short* qallb  = (unsigned short*)carve((size_t)T_ * Ee * Dd * 2);
  unsigned short* xeg    = (unsigned short*)carve((size_t)T_ * KR * 2);

  // merged weight conversion + gate1
  prep_kernel<<<1412, 256, 0, stream>>>(
      W_in, W_out, b_out, W_kv, BqkvT, BrT, BkvT, x, wg, lgate, xb);

  // merged gate2 + qkv GEMM (independent; gate2 hidden under GEMM)
  qkv_gate2_kernel<<<NB2 + (T_ / 64) * 26, 256, 0, stream>>>(
      xb, BqkvT, b_in, b_kv, qallb, kbuf, vtbuf,
      lgate, idx, gate, bstats, xeg);

  // attention with fused combine epilogue -> xeg
  attn_kernel<<<dim3(Nn / 64, Bb * Hh), 256, 0, stream>>>(
      qallb, idx, gate, kbuf, vtbuf, xeg);

  // merged reduce GEMM + aux1
  reduce_aux_kernel<<<768 + 49, 256, 0, stream>>>(
      xeg, BrT, out, bstats, stats2);

  // aux2 finalize
  aux2_kernel<<<1, 64, 0, stream>>>(stats2, out, out_size);
}

// Round 15
// 173.939 us; speedup vs baseline: 1.1109x; 1.0195x over previous
//
#include <hip/hip_runtime.h>
#include <hip/hip_bf16.h>

// Problem constants
#define T_  4096
#define Bb  2
#define Nn  2048
#define Cc  768
#define Ee  24
#define Dd  64
#define Hh  12
#define KR  1600   // reduce GEMM K: 1536 (W_out) + 24 (b_out) + 40 pad (mult of 64)
#define KS  16     // gate k-split
#define KC  48     // 768 / KS
#define NB2 1024   // gate2 block count (T_/4)
#define SCL 0.18033688f   // 0.125 * log2(e) — folded into q at GEMM epilogue

typedef __attribute__((ext_vector_type(8))) short bf16x8;
typedef __attribute__((ext_vector_type(4))) short bf16x4;
typedef __attribute__((ext_vector_type(4))) float f32x4;
typedef __attribute__((ext_vector_type(8))) unsigned short u16x8;

__device__ __forceinline__ unsigned short f2bf(float f) {
  union { float f; unsigned int i; } u; u.f = f;
  unsigned int r = u.i + 0x7FFFu + ((u.i >> 16) & 1u);
  return (unsigned short)(r >> 16);
}

__device__ __forceinline__ void gload16(const void* g, void* l) {
  __builtin_amdgcn_global_load_lds(
      (const __attribute__((address_space(1))) void*)g,
      (__attribute__((address_space(3))) void*)l, 16, 0, 0);
}

// ---------------------------------------------------------------------------
// MERGED prep kernel (R13 win config — unchanged): weight conversion + gate1.
//   blocks [0,288)     : W_in -> BqT
//   blocks [288,888)   : [W_out;b_out;pad] -> BrT
//   blocks [888,900)   : W_kv -> BkvT
//   blocks [900,1412)  : gate1 (512 blocks: 32 t-chunks x 16 k-slices)
// ---------------------------------------------------------------------------
#define XPAD 52
__global__ __launch_bounds__(256) void prep_kernel(
    const float* __restrict__ W_in, const float* __restrict__ W_out,
    const float* __restrict__ b_out, const float* __restrict__ W_kv,
    unsigned short* __restrict__ BqT, unsigned short* __restrict__ BrT,
    unsigned short* __restrict__ BkvT,
    const float* __restrict__ x, const float* __restrict__ wg,
    float* __restrict__ partial, unsigned short* __restrict__ xb)
{
  __shared__ __align__(16) float smem[64 * 129];   // 33 KB (max of both uses)
  const int bid = blockIdx.x, tid = threadIdx.x;

  if (bid < 900) {
    float* ls = smem;
    if (bid < 288) {
      const int e = bid / 12, c0 = (bid % 12) * 64;
      #pragma unroll
      for (int i = 0; i < 16; ++i) {
        int L = tid + i * 256, c = L >> 6, d = L & 63;
        ls[c * 65 + d] = W_in[(size_t)e * Cc * Dd + (size_t)(c0 + c) * Dd + d];
      }
      __syncthreads();
      #pragma unroll
      for (int i = 0; i < 16; ++i) {
        int L = tid + i * 256, d = L >> 6, c = L & 63;
        BqT[(size_t)(e * Dd + d) * Cc + c0 + c] = f2bf(ls[c * 65 + d]);
      }
    } else if (bid < 888) {
      const int i2 = bid - 288;
      const int k0 = (i2 / 12) * 32, n0 = (i2 % 12) * 64;
      #pragma unroll
      for (int i = 0; i < 8; ++i) {
        int L = tid + i * 256, k = L >> 6, n = L & 63;
        int kk = k0 + k;
        float v = (kk < 1536) ? W_out[(size_t)kk * Cc + n0 + n]
                : (kk < 1560) ? b_out[(size_t)(kk - 1536) * Cc + n0 + n] : 0.f;
        ls[k * 65 + n] = v;
      }
      __syncthreads();
      #pragma unroll
      for (int i = 0; i < 8; ++i) {
        int L = tid + i * 256, n = L >> 5, k = L & 31;
        BrT[(size_t)(n0 + n) * KR + k0 + k] = f2bf(ls[k * 65 + n]);
      }
    } else {
      const int c0 = (bid - 888) * 64;
      #pragma unroll
      for (int i = 0; i < 32; ++i) {
        int L = tid + i * 256, c = L >> 7, j = L & 127;
        ls[c * 129 + j] = W_kv[(size_t)(c0 + c) * 128 + j];
      }
      __syncthreads();
      #pragma unroll
      for (int i = 0; i < 32; ++i) {
        int L = tid + i * 256, j = L >> 6, c = L & 63;
        BkvT[(size_t)j * Cc + c0 + c] = f2bf(ls[c * 129 + j]);
      }
    }
  } else {
    // ---- gate1: 128 tokens/block, 2 threads per token ----
    float* xs  = smem;                 // 128 * XPAD floats
    float* wsT = smem + 128 * XPAD;    // Ee * KC floats
    const int g = bid - 900;
    const int t0 = (g & 31) * 128;
    const int s = g >> 5, k0 = s * KC;

    #pragma unroll
    for (int i = 0; i < 6; ++i) {
      int f = tid + i * 256;
      int token = f / 12, j = f % 12;
      size_t gofs = (size_t)(t0 + token) * Cc + k0 + j * 4;
      float4 v = *(const float4*)&x[gofs];
      *(float4*)&xs[token * XPAD + j * 4] = v;
      ushort4 o;
      o.x = f2bf(v.x); o.y = f2bf(v.y); o.z = f2bf(v.z); o.w = f2bf(v.w);
      *(ushort4*)&xb[gofs] = o;
    }
    for (int i = tid; i < Ee * KC; i += 256)
      wsT[(i % Ee) * KC + i / Ee] = wg[k0 * Ee + i];
    __syncthreads();

    const int token = tid >> 1, half = tid & 1;
    float xr[KC];
    #pragma unroll
    for (int kg = 0; kg < KC / 4; ++kg)
      *(float4*)&xr[kg * 4] = *(const float4*)&xs[token * XPAD + kg * 4];

    float acc[12];
    #pragma unroll
    for (int e = 0; e < 12; ++e) acc[e] = 0.f;
    #pragma unroll
    for (int e = 0; e < 12; ++e) {
      const int eg = half * 12 + e;
      #pragma unroll
      for (int kg = 0; kg < KC / 4; ++kg) {
        float4 wv = *(const float4*)&wsT[eg * KC + kg * 4];
        acc[e] += xr[kg * 4 + 0] * wv.x + xr[kg * 4 + 1] * wv.y
                + xr[kg * 4 + 2] * wv.z + xr[kg * 4 + 3] * wv.w;
      }
    }

    float* dst = partial + ((size_t)(t0 + token) * KS + s) * Ee + half * 12;
    #pragma unroll
    for (int eg2 = 0; eg2 < 3; ++eg2)
      *(float4*)&dst[eg2 * 4] = *(float4*)&acc[eg2 * 4];
  }
}

// ---------------------------------------------------------------------------
// Shared 64x64 BK=64 GEMM body (R9/R10 validated structure): 2-phase double
// buffer, attn-style XOR-swizzled staging/reads (zero bank conflicts).
// AsB/BsB point into the caller's 32 KB LDS (2 x 4096 shorts each).
// MODE 0: f32 out (reduce).  MODE 1: fused qall+kv epilogue.
// ---------------------------------------------------------------------------
template<int MODE>
__device__ __forceinline__ void gemm64_body(
    int m0, int n0, unsigned short* AsB, unsigned short* BsB,
    const unsigned short* __restrict__ A, const unsigned short* __restrict__ BT,
    const float* __restrict__ bias, const float* __restrict__ bias2,
    void* __restrict__ Cout, void* __restrict__ Cout2, void* __restrict__ Cout3,
    int K, int ldc)
{
  constexpr int MI = 2, NI = 2;
  const int tid = threadIdx.x, w = tid >> 6, lane = tid & 63;
  const int quad = lane >> 4, nl = lane & 15;
  const int mw = (w & 1) * 32, nw = (w >> 1) * 32;

  f32x4 acc[MI][NI];
  #pragma unroll
  for (int i = 0; i < MI; ++i)
    #pragma unroll
    for (int j = 0; j < NI; ++j) acc[i][j] = (f32x4){0.f, 0.f, 0.f, 0.f};

  const int sr  = lane >> 3;
  const int cbd = (lane & 7) ^ sr;
  const int xl  = nl & 7;
  const int ca0 = (quad ^ xl) * 8;
  const int ca1 = ((quad + 4) ^ xl) * 8;

  const unsigned short* abase = A + (size_t)(m0 + w * 16 + sr) * K + cbd * 8;
  const unsigned short* bbase = BT + (size_t)(n0 + w * 16 + sr) * K + cbd * 8;

  auto STAGE = [&](int bi, int k0) {
    #pragma unroll
    for (int i = 0; i < 2; ++i) {
      gload16(abase + (size_t)(i * 8) * K + k0, AsB + bi * 4096 + (w * 16 + i * 8) * 64);
      gload16(bbase + (size_t)(i * 8) * K + k0, BsB + bi * 4096 + (w * 16 + i * 8) * 64);
    }
  };

  const int nt = K / 64;
  STAGE(0, 0);
  __syncthreads();
  for (int t = 0; t < nt; ++t) {
    const int cur = t & 1;
    if (t + 1 < nt) STAGE(cur ^ 1, (t + 1) * 64);   // issue next BEFORE compute

    const unsigned short* Ac = AsB + cur * 4096;
    const unsigned short* Bc = BsB + cur * 4096;
    bf16x8 af0[MI], af1[MI], bf0[NI], bf1[NI];
    #pragma unroll
    for (int mi = 0; mi < MI; ++mi) {
      const unsigned short* ar = &Ac[(mw + mi * 16 + nl) * 64];
      af0[mi] = *(const bf16x8*)(ar + ca0);
      af1[mi] = *(const bf16x8*)(ar + ca1);
    }
    #pragma unroll
    for (int ni = 0; ni < NI; ++ni) {
      const unsigned short* br = &Bc[(nw + ni * 16 + nl) * 64];
      bf0[ni] = *(const bf16x8*)(br + ca0);
      bf1[ni] = *(const bf16x8*)(br + ca1);
    }
    #pragma unroll
    for (int mi = 0; mi < MI; ++mi)
      #pragma unroll
      for (int ni = 0; ni < NI; ++ni) {
        acc[mi][ni] = __builtin_amdgcn_mfma_f32_16x16x32_bf16(
            af0[mi], bf0[ni], acc[mi][ni], 0, 0, 0);
        acc[mi][ni] = __builtin_amdgcn_mfma_f32_16x16x32_bf16(
            af1[mi], bf1[ni], acc[mi][ni], 0, 0, 0);
      }

    __syncthreads();
  }

  #pragma unroll
  for (int mi = 0; mi < MI; ++mi) {
    int rowb = m0 + mw + mi * 16 + quad * 4;
    int bb = rowb >> 11, nn = rowb & (Nn - 1);
    #pragma unroll
    for (int ni = 0; ni < NI; ++ni) {
      int col = n0 + nw + ni * 16 + nl;
      if (MODE == 0) {
        #pragma unroll
        for (int reg = 0; reg < 4; ++reg)
          ((float*)Cout)[(size_t)(rowb + reg) * ldc + col] = acc[mi][ni][reg];
      } else {
        if (col < 1536) {
          float bv = bias[col];
          #pragma unroll
          for (int reg = 0; reg < 4; ++reg)
            ((unsigned short*)Cout)[(size_t)(rowb + reg) * 1536 + col] =
                f2bf((acc[mi][ni][reg] + bv) * SCL);
        } else {
          int c2 = col - 1536;
          float bv = bias2[c2];
          if (c2 < Dd) {
            #pragma unroll
            for (int reg = 0; reg < 4; ++reg)
              ((unsigned short*)Cout2)[((size_t)bb * Nn + nn + reg) * Dd + c2] =
                  f2bf(acc[mi][ni][reg] + bv);
          } else {
            int p6 = nn & 63;
            int np = (nn & ~63) | (p6 & 0x23)
                   | (((p6 >> 4) & 1) << 2) | (((p6 >> 2) & 3) << 3);
            ushort4 v;
            v.x = f2bf(acc[mi][ni][0] + bv);
            v.y = f2bf(acc[mi][ni][1] + bv);
            v.z = f2bf(acc[mi][ni][2] + bv);
            v.w = f2bf(acc[mi][ni][3] + bv);
            *(ushort4*)((unsigned short*)Cout3 +
                        ((size_t)bb * Dd + (c2 - Dd)) * Nn + np) = v;
          }
        }
      }
    }
  }
}

// ---------------------------------------------------------------------------
// MERGED gate2 + qkv GEMM (R14 win config — unchanged).
//   blocks [0,1024)      : gate2 (softmax/top-k/stats + xeg row prep)
//   blocks [1024,2688)   : qkv GEMM, m-fastest decode
// ---------------------------------------------------------------------------
__global__ __launch_bounds__(256) void qkv_gate2_kernel(
    const unsigned short* __restrict__ xb, const unsigned short* __restrict__ BqkvT,
    const float* __restrict__ b_in, const float* __restrict__ b_kv,
    unsigned short* __restrict__ qallb, unsigned short* __restrict__ kbuf,
    unsigned short* __restrict__ vtbuf,
    const float* __restrict__ partial, int* __restrict__ idx,
    float* __restrict__ gate, float* __restrict__ bstats,
    unsigned short* __restrict__ xeg)
{
  __shared__ __align__(16) char smem[65536 / 2];   // 32 KB
  const int bid = blockIdx.x, tid = threadIdx.x;

  if (bid >= NB2) {
    const int b2 = bid - NB2;
    const int m0 = (b2 & 63) * 64, n0 = (b2 >> 6) * 64;
    gemm64_body<1>(m0, n0, (unsigned short*)smem, (unsigned short*)smem + 8192,
                   xb, BqkvT, b_in, b_kv, qallb, kbuf, vtbuf, Cc, 1536);
    return;
  }

  // ---- gate2 ----
  float* xls  = (float*)smem;                       // [4][KS*Ee] = 1536 f
  float* sacc = xls + 4 * KS * Ee;                  // 49 f (pad to 64)
  unsigned short* dens = (unsigned short*)(sacc + 64);  // [4][64]
  const int w = tid >> 6, lane = tid & 63;
  const int t = bid * 4 + w;

  if (tid < 49) sacc[tid] = 0.f;
  dens[w * 64 + lane] = 0;

  const float* p = partial + (size_t)t * (KS * Ee);
  #pragma unroll
  for (int i = 0; i < 6; ++i) xls[w * (KS * Ee) + lane + i * 64] = p[lane + i * 64];

  // zero-fill xeg cols [0,1536) for this token (3 x ushort8 per lane)
  {
    u16x8 z = (u16x8){0, 0, 0, 0, 0, 0, 0, 0};
    unsigned short* xrow = xeg + (size_t)t * KR;
    #pragma unroll
    for (int i = 0; i < 3; ++i)
      *(u16x8*)&xrow[(lane + i * 64) * 8] = z;
  }

  float logit = -1e30f;
  if (lane < Ee) {
    float acc = 0.f;
    #pragma unroll
    for (int s = 0; s < KS; ++s) acc += xls[w * (KS * Ee) + s * Ee + lane];
    logit = acc;
  }
  float m = logit;
  for (int o = 32; o; o >>= 1) m = fmaxf(m, __shfl_xor(m, o));
  float pr = (lane < Ee) ? expf(logit - m) : 0.f;
  float s = pr;
  for (int o = 32; o; o >>= 1) s += __shfl_xor(s, o);
  float prob = pr / s;
  float lse = m + logf(s);

  bool sel = false;
  float my_p = 0.f; int my_e = -1;
  for (int h = 0; h < Hh; ++h) {
    float v = (lane < Ee && !sel) ? prob : -1.f;
    int ix = lane;
    for (int o = 32; o; o >>= 1) {
      float ov = __shfl_xor(v, o); int oi = __shfl_xor(ix, o);
      if (ov > v || (ov == v && oi < ix)) { v = ov; ix = oi; }
    }
    if (lane == ix) sel = true;
    if (lane == h) { my_p = v; my_e = ix; }
  }
  float gsum = (lane < Hh) ? my_p : 0.f;
  for (int o = 32; o; o >>= 1) gsum += __shfl_xor(gsum, o);
  float gval = my_p / (gsum + 1e-6f);
  if (lane < Hh) {
    idx[t * Hh + lane] = my_e;
    gate[t * Hh + lane] = gval;
  }

  __syncthreads();
  if (lane < Ee) atomicAdd(&sacc[lane], prob);
  if (lane < Hh) {
    atomicAdd(&sacc[24 + my_e], 1.0f);
    dens[w * 64 + my_e] = f2bf(gval);
  }
  if (lane == 0) atomicAdd(&sacc[48], lse * lse);
  __syncthreads();
  if (tid < 49) bstats[(size_t)tid * NB2 + bid] = sacc[tid];

  // dense-gate + pad cols [1536,1600): one short per lane
  xeg[(size_t)t * KR + 1536 + lane] = dens[w * 64 + lane];
}

// ---------------------------------------------------------------------------
// MERGED flash attention + aux1 (aux1 reads bstats from the PREVIOUS
// dispatch; its ~49 tiny blocks hide under attn's 40us).  Flat 1D grid:
//   blocks [0,768)   : attn (x = bid & 31, bh = bid >> 5) — R10 win config
//   blocks [768,817) : aux1 (bstats row-sum -> stats2)
// ---------------------------------------------------------------------------
__global__ __launch_bounds__(256, 3) void attn_aux1_kernel(
    const unsigned short* __restrict__ qallb, const int* __restrict__ idx,
    const float* __restrict__ gate,
    const unsigned short* __restrict__ kbuf, const unsigned short* __restrict__ vtbuf,
    unsigned short* __restrict__ xeg,
    const float* __restrict__ bstats, float* __restrict__ stats2)
{
  __shared__ __align__(16) unsigned short ksl[3][64 * 64];  // K tiles [key][d], swizzled
  __shared__ __align__(16) unsigned short vtl[3][64 * 64];  // V^T tiles [d][key-perm]

  const int bid = blockIdx.x;
  const int tid = threadIdx.x;

  if (bid >= 768) {
    // ---- aux1: bstats row-sum -> stats2[j] ----
    float* r = (float*)ksl;
    const int j = bid - 768;
    float4 v = *(const float4*)&bstats[(size_t)j * NB2 + tid * 4];
    float s = (v.x + v.y) + (v.z + v.w);
    for (int o = 32; o; o >>= 1) s += __shfl_xor(s, o);
    if ((tid & 63) == 0) r[tid >> 6] = s;
    __syncthreads();
    if (tid == 0) stats2[j] = (r[0] + r[1]) + (r[2] + r[3]);
    return;
  }

  const int w = tid >> 6, lane = tid & 63;
  const int quad = lane >> 4, nl = lane & 15;
  const int bh = bid >> 5;                      // 24 head-batches
  const int b = bh / Hh, h = bh - b * Hh;
  const int qw = (bid & 31) * 64 + w * 16;      // wave's 16 queries

  const int tq = b * Nn + qw + nl;
  const int eq = idx[tq * Hh + h];
  const unsigned short* qrow = qallb + (size_t)tq * (Ee * Dd) + eq * Dd + quad * 8;
  const bf16x8 qB0 = *(const bf16x8*)(qrow);
  const bf16x8 qB1 = *(const bf16x8*)(qrow + 32);

  f32x4 acc[4];
  #pragma unroll
  for (int dg = 0; dg < 4; ++dg) acc[dg] = (f32x4){0.f, 0.f, 0.f, 0.f};
  float l = 0.f;

  const int sr  = lane >> 3;
  const int cbd = (lane & 7) ^ sr;              // XOR-swizzled source chunk
  const int xl  = nl & 7;
  const int ca0 = (quad ^ xl) * 8;              // b128 chunk offsets (K and V)
  const int ca1 = ((quad + 4) ^ xl) * 8;

  const unsigned short* kgbase =
      kbuf + ((size_t)b * Nn + w * 16 + sr) * Dd + cbd * 8;
  const unsigned short* vgbase =
      vtbuf + ((size_t)b * Dd + w * 16 + sr) * Nn + cbd * 8;

  auto STAGE = [&](int bi, int t) {
    const int j0 = t * 64;
    #pragma unroll
    for (int i = 0; i < 2; ++i) {
      gload16(kgbase + (size_t)(j0 + i * 8) * Dd, &ksl[bi][(w * 16 + i * 8) * 64]);
      gload16(vgbase + (size_t)(i * 8) * Nn + j0, &vtl[bi][(w * 16 + i * 8) * 64]);
    }
  };

  auto COMPUTE = [&](const unsigned short* ks_, const unsigned short* vt_) {
    __builtin_amdgcn_s_setprio(1);
    bf16x4 pf[4];
    #pragma unroll
    for (int kg = 0; kg < 4; ++kg) {
      const unsigned short* kr = ks_ + (kg * 16 + nl) * 64;
      bf16x8 a0 = *(const bf16x8*)(kr + ca0);
      bf16x8 a1 = *(const bf16x8*)(kr + ca1);
      f32x4 c = {0.f, 0.f, 0.f, 0.f};
      c = __builtin_amdgcn_mfma_f32_16x16x32_bf16(a0, qB0, c, 0, 0, 0);
      c = __builtin_amdgcn_mfma_f32_16x16x32_bf16(a1, qB1, c, 0, 0, 0);
      float p0 = __builtin_amdgcn_exp2f(c[0]);
      float p1 = __builtin_amdgcn_exp2f(c[1]);
      float p2 = __builtin_amdgcn_exp2f(c[2]);
      float p3 = __builtin_amdgcn_exp2f(c[3]);
      l += (p0 + p1) + (p2 + p3);
      union { __hip_bfloat162 h2[2]; bf16x4 v; } pk;
      pk.h2[0] = __float22bfloat162_rn(float2{p0, p1});
      pk.h2[1] = __float22bfloat162_rn(float2{p2, p3});
      pf[kg] = pk.v;
    }
    bf16x8 pb0 = __builtin_shufflevector(pf[0], pf[1], 0, 1, 2, 3, 4, 5, 6, 7);
    bf16x8 pb1 = __builtin_shufflevector(pf[2], pf[3], 0, 1, 2, 3, 4, 5, 6, 7);
    #pragma unroll
    for (int dg = 0; dg < 4; ++dg) {
      const unsigned short* vrow = vt_ + (dg * 16 + nl) * 64;
      bf16x8 v0 = *(const bf16x8*)(vrow + ca0);
      bf16x8 v1 = *(const bf16x8*)(vrow + ca1);
      acc[dg] = __builtin_amdgcn_mfma_f32_16x16x32_bf16(v0, pb0, acc[dg], 0, 0, 0);
      acc[dg] = __builtin_amdgcn_mfma_f32_16x16x32_bf16(v1, pb1, acc[dg], 0, 0, 0);
    }
    __builtin_amdgcn_s_setprio(0);
  };

  STAGE(0, 0);
  STAGE(1, 1);
  #pragma unroll 1
  for (int t = 0; t < 30; t += 3) {
    STAGE(2, t + 2);
    asm volatile("s_waitcnt vmcnt(8)" ::: "memory");
    __builtin_amdgcn_s_barrier();
    __builtin_amdgcn_sched_barrier(0);
    COMPUTE(ksl[0], vtl[0]);
    __builtin_amdgcn_sched_barrier(0);
    asm volatile("" ::: "memory");
    __builtin_amdgcn_s_barrier();

    STAGE(0, t + 3);
    asm volatile("s_waitcnt vmcnt(8)" ::: "memory");
    __builtin_amdgcn_s_barrier();
    __builtin_amdgcn_sched_barrier(0);
    COMPUTE(ksl[1], vtl[1]);
    __builtin_amdgcn_sched_barrier(0);
    asm volatile("" ::: "memory");
    __builtin_amdgcn_s_barrier();

    STAGE(1, t + 4);
    asm volatile("s_waitcnt vmcnt(8)" ::: "memory");
    __builtin_amdgcn_s_barrier();
    __builtin_amdgcn_sched_barrier(0);
    COMPUTE(ksl[2], vtl[2]);
    __builtin_amdgcn_sched_barrier(0);
    asm volatile("" ::: "memory");
    __builtin_amdgcn_s_barrier();
  }
  asm volatile("s_waitcnt vmcnt(4)" ::: "memory");
  __builtin_amdgcn_s_barrier();
  __builtin_amdgcn_sched_barrier(0);
  COMPUTE(ksl[0], vtl[0]);
  __builtin_amdgcn_sched_barrier(0);
  asm volatile("s_waitcnt vmcnt(0)" ::: "memory");
  __builtin_amdgcn_s_barrier();
  __builtin_amdgcn_sched_barrier(0);
  COMPUTE(ksl[1], vtl[1]);

  // ---- fused combine epilogue: xeg[tq][eq*64 + d] = f2bf(gate * o / l) ----
  float lg = l;
  lg += __shfl_xor(lg, 16);
  lg += __shfl_xor(lg, 32);
  const float scale = gate[tq * Hh + h] / lg;
  unsigned short* xrow = xeg + (size_t)tq * KR + eq * Dd + quad * 4;
  #pragma unroll
  for (int dg = 0; dg < 4; ++dg) {
    ushort4 v;
    v.x = f2bf(acc[dg][0] * scale);
    v.y = f2bf(acc[dg][1] * scale);
    v.z = f2bf(acc[dg][2] * scale);
    v.w = f2bf(acc[dg][3] * scale);
    *(ushort4*)(xrow + dg * 16) = v;
  }
}

// ---------------------------------------------------------------------------
// MERGED reduce GEMM + aux2 (aux2 reads stats2 from the PREVIOUS dispatch).
//   blocks [0,768) : reduce GEMM m-fastest;  block 768 : aux2 finalize
// ---------------------------------------------------------------------------
__global__ __launch_bounds__(256) void reduce_aux2_kernel(
    const unsigned short* __restrict__ xeg, const unsigned short* __restrict__ BrT,
    float* __restrict__ out,
    const float* __restrict__ stats2, int out_size)
{
  __shared__ __align__(16) char smem[65536 / 2];   // 32 KB
  const int bid = blockIdx.x, tid = threadIdx.x;

  if (bid >= 768) {
    // ---- aux2 finalize (wave 0 only) ----
    if (tid >= 64) return;
    const int lane = tid;
    float a = (lane < Ee) ? stats2[lane] : 0.f;
    float b = (lane < Ee) ? stats2[24 + lane] : 0.f;
    float pt = a, ft = b, sw = a * b;
    for (int o = 32; o; o >>= 1) {
      pt += __shfl_xor(pt, o); ft += __shfl_xor(ft, o); sw += __shfl_xor(sw, o);
    }
    if (lane == 0) {
      float sswitch = (float)Ee * sw / (pt * ft);
      float z = stats2[48] * (1.0f / (float)T_);
      out[out_size - 1] = 0.1f * sswitch + 0.001f * z;
    }
    return;
  }

  const int m0 = (bid & 63) * 64, n0 = (bid >> 6) * 64;
  gemm64_body<0>(m0, n0, (unsigned short*)smem, (unsigned short*)smem + 8192,
                 xeg, BrT, nullptr, nullptr, out, nullptr, nullptr, KR, Cc);
}

// ---------------------------------------------------------------------------
extern "C" void kernel_launch(void* const* d_in, const int* in_sizes, int n_in,
                              void* d_out, int out_size, void* d_ws, size_t ws_size,
                              hipStream_t stream)
{
  const float* x     = (const float*)d_in[0];
  const float* wg    = (const float*)d_in[1];
  const float* W_in  = (const float*)d_in[2];
  const float* b_in  = (const float*)d_in[3];
  const float* W_out = (const float*)d_in[4];
  const float* b_out = (const float*)d_in[5];
  const float* W_kv  = (const float*)d_in[6];
  const float* b_kv  = (const float*)d_in[7];
  float* out = (float*)d_out;

  char* ws = (char*)d_ws;
  size_t off = 0;
  auto carve = [&](size_t bytes) -> void* {
    void* p = ws + off;
    off = (off + bytes + 255) & ~(size_t)255;
    return p;
  };
  int*            idx    = (int*)           carve((size_t)T_ * Hh * 4);
  float*          gate   = (float*)         carve((size_t)T_ * Hh * 4);
  float*          bstats = (float*)         carve((size_t)49 * NB2 * 4);
  float*          stats2 = (float*)         carve(256);
  float*          lgate  = (float*)         carve((size_t)T_ * KS * Ee * 4);
  unsigned short* xb     = (unsigned short*)carve((size_t)T_ * Cc * 2);
  unsigned short* BqkvT  = (unsigned short*)carve((size_t)(Ee * Dd + 128) * Cc * 2);
  unsigned short* BkvT   = BqkvT + (size_t)Ee * Dd * Cc;
  unsigned short* BrT    = (unsigned short*)carve((size_t)Cc * KR * 2);
  unsigned short* kbuf   = (unsigned short*)carve((size_t)T_ * Dd * 2);
  unsigned short* vtbuf  = (unsigned short*)carve((size_t)T_ * Dd * 2);
  unsigned short* qallb  = (unsigned short*)carve((size_t)T_ * Ee * Dd * 2);
  unsigned short* xeg    = (unsigned short*)carve((size_t)T_ * KR * 2);

  // 1) merged weight conversion + gate1
  prep_kernel<<<1412, 256, 0, stream>>>(
      W_in, W_out, b_out, W_kv, BqkvT, BrT, BkvT, x, wg, lgate, xb);

  // 2) merged gate2 + qkv GEMM
  qkv_gate2_kernel<<<NB2 + (T_ / 64) * 26, 256, 0, stream>>>(
      xb, BqkvT, b_in, b_kv, qallb, kbuf, vtbuf,
      lgate, idx, gate, bstats, xeg);

  // 3) merged attention (fused combine epilogue) + aux1
  attn_aux1_kernel<<<768 + 49, 256, 0, stream>>>(
      qallb, idx, gate, kbuf, vtbuf, xeg, bstats, stats2);

  // 4) merged reduce GEMM + aux2 finalize
  reduce_aux2_kernel<<<768 + 1, 256, 0, stream>>>(
      xeg, BrT, out, stats2, out_size);
}